// Round 5
// baseline (378.832 us; speedup 1.0000x reference)
//
#include <hip/hip_runtime.h>
#include <math.h>

// Problem constants
#define BATCH 8
#define CH    256
#define HDIM  56
#define WDIM  56
#define HW    (HDIM*WDIM)          // 3136
#define MTOT  (BATCH*HW)           // 25088
#define GRP   8
#define GC    32
#define NP    9                    // K*K
#define NOFF  (GRP*NP*2)           // 144
#define NMSK  (GRP*NP)             // 72
#define POSB  4                    // positions per sample block

// ---------------------------------------------------------------------------
// GEMM 1: v[m][n] = sum_k x[b][k][hw] * w_in[k][n] + b_in[n]
// 128x128 tile, 8x8 micro-tile (2x2 of float4 at offsets {0,64}).
// n-fast map: NHWC float4 stores coalesce. A (x) is m-contiguous per k row.
// ---------------------------------------------------------------------------
__global__ __launch_bounds__(256)
void gemm_in_kernel(const float* __restrict__ x,
                    const float* __restrict__ w_in,
                    const float* __restrict__ b_in,
                    float* __restrict__ v)
{
    __shared__ alignas(16) float As[16][128];
    __shared__ alignas(16) float Bs[16][128];
    const int m0 = blockIdx.x * 128;
    const int n0 = blockIdx.y * 128;
    const int t = threadIdx.x;
    const int lk  = t >> 4;            // staging k 0..15
    const int lm4 = (t & 15) * 4;      // staging m/n 0..60
    const int tm4 = (t >> 4) * 4;      // micro rows base (n-fast)
    const int tn4 = (t & 15) * 4;      // micro cols base
    float acc[8][8] = {};

    // batch-safe A chunk bases (HW%4==0 -> a float4 chunk never crosses batch)
    const int mA0 = m0 + lm4, mA1 = m0 + lm4 + 64;
    const size_t aoff0 = (size_t)(mA0 / HW) * CH * HW + (mA0 % HW);
    const size_t aoff1 = (size_t)(mA1 / HW) * CH * HW + (mA1 % HW);

    for (int k0 = 0; k0 < CH; k0 += 16) {
        const int k = k0 + lk;
        const float4 a0 = *(const float4*)(x + aoff0 + (size_t)k * HW);
        const float4 a1 = *(const float4*)(x + aoff1 + (size_t)k * HW);
        const float4 b0 = *(const float4*)(w_in + (size_t)k * CH + n0 + lm4);
        const float4 b1 = *(const float4*)(w_in + (size_t)k * CH + n0 + lm4 + 64);
        *(float4*)&As[lk][lm4]      = a0;
        *(float4*)&As[lk][lm4 + 64] = a1;
        *(float4*)&Bs[lk][lm4]      = b0;
        *(float4*)&Bs[lk][lm4 + 64] = b1;
        __syncthreads();
        #pragma unroll
        for (int kk = 0; kk < 16; ++kk) {
            const float4 aA = *(const float4*)&As[kk][tm4];
            const float4 aB = *(const float4*)&As[kk][tm4 + 64];
            const float4 bA = *(const float4*)&Bs[kk][tn4];
            const float4 bB = *(const float4*)&Bs[kk][tn4 + 64];
            const float av[8] = {aA.x, aA.y, aA.z, aA.w, aB.x, aB.y, aB.z, aB.w};
            const float bv[8] = {bA.x, bA.y, bA.z, bA.w, bB.x, bB.y, bB.z, bB.w};
            #pragma unroll
            for (int i = 0; i < 8; ++i)
                #pragma unroll
                for (int j = 0; j < 8; ++j) acc[i][j] += av[i] * bv[j];
        }
        __syncthreads();
    }
    const float4 biasA = *(const float4*)&b_in[n0 + tn4];
    const float4 biasB = *(const float4*)&b_in[n0 + tn4 + 64];
    #pragma unroll
    for (int i = 0; i < 8; ++i) {
        const int m = m0 + (i < 4 ? tm4 + i : 64 + tm4 + i - 4);
        float4 o0, o1;
        o0.x = acc[i][0] + biasA.x; o0.y = acc[i][1] + biasA.y;
        o0.z = acc[i][2] + biasA.z; o0.w = acc[i][3] + biasA.w;
        o1.x = acc[i][4] + biasB.x; o1.y = acc[i][5] + biasB.y;
        o1.z = acc[i][6] + biasB.z; o1.w = acc[i][7] + biasB.w;
        *(float4*)&v[(size_t)m * CH + n0 + tn4]      = o0;
        *(float4*)&v[(size_t)m * CH + n0 + tn4 + 64] = o1;
    }
}

// ---------------------------------------------------------------------------
// Fused depthwise 3x3 + bias + LayerNorm(C) + exact GELU -> f (NHWC)
// ---------------------------------------------------------------------------
__global__ __launch_bounds__(256)
void dw_ln_gelu_kernel(const float* __restrict__ x,
                       const float* __restrict__ dw_w,
                       const float* __restrict__ dw_b,
                       const float* __restrict__ ln_g,
                       const float* __restrict__ ln_b,
                       float* __restrict__ f)
{
    __shared__ float tile[WDIM][CH + 1];    // 56 x 257 floats (57.5 KB)
    __shared__ float red1[WDIM][4], red2[WDIM][4];
    __shared__ float meanA[WDIM], rstdA[WDIM];

    const int h = blockIdx.x;
    const int b = blockIdx.y;
    const int t = threadIdx.x;
    const int lane = t & 63;
    const int wv   = t >> 6;               // wave id 0..3

    // ---- Phase 1: depthwise conv, 4 channels (one per wave) per iteration
    for (int cg = 0; cg < CH / 4; ++cg) {
        const int c = cg * 4 + wv;
        const float* xp = x + ((size_t)b * CH + c) * HW;
        float rowv[3];
        #pragma unroll
        for (int r = 0; r < 3; ++r) {
            const int hh = h + r - 1;
            rowv[r] = (lane < WDIM && hh >= 0 && hh < HDIM) ? xp[hh * WDIM + lane] : 0.0f;
        }
        const float* wp = dw_w + c * 9;     // wave-uniform -> scalar loads
        float acc = dw_b[c];
        #pragma unroll
        for (int r = 0; r < 3; ++r) {
            float L = __shfl_up(rowv[r], 1);
            float R = __shfl_down(rowv[r], 1);
            if (lane == 0) L = 0.0f;
            acc += L * wp[r * 3 + 0] + rowv[r] * wp[r * 3 + 1] + R * wp[r * 3 + 2];
        }
        if (lane < WDIM)
            tile[lane][c] = acc;
    }
    __syncthreads();

    // ---- Phase 2: LN statistics per position
    if (t < 224) {
        const int p = t >> 2, q = t & 3;
        float s1 = 0.0f, s2 = 0.0f;
        #pragma unroll 8
        for (int i = 0; i < 64; ++i) {
            const float v = tile[p][q * 64 + i];
            s1 += v; s2 += v * v;
        }
        red1[p][q] = s1; red2[p][q] = s2;
    }
    __syncthreads();
    if (t < WDIM) {
        const float s1 = red1[t][0] + red1[t][1] + red1[t][2] + red1[t][3];
        const float s2 = red2[t][0] + red2[t][1] + red2[t][2] + red2[t][3];
        const float m = s1 * (1.0f / 256.0f);
        const float var = s2 * (1.0f / 256.0f) - m * m;
        meanA[t] = m;
        rstdA[t] = rsqrtf(var + 1e-5f);
    }
    __syncthreads();

    // ---- Phase 3: normalize + GELU + coalesced NHWC store
    const float gam = ln_g[t], bet = ln_b[t];
    const size_t n0 = (size_t)(b * HDIM + h) * WDIM;
    for (int p = 0; p < WDIM; ++p) {
        const float xn = (tile[p][t] - meanA[p]) * rstdA[p] * gam + bet;
        const float g = 0.5f * xn * (1.0f + erff(xn * 0.70710678118654752f));
        f[(n0 + p) * CH + t] = g;
    }
}

// ---------------------------------------------------------------------------
// GEMM (A row-major [M,256]) -> Cout [M,N] = A @ Bw + bias. 4x4 micro-tile.
// ---------------------------------------------------------------------------
__global__ __launch_bounds__(256)
void gemm_rowA_kernel(const float* __restrict__ A,
                      const float* __restrict__ Bw,
                      const float* __restrict__ bias,
                      float* __restrict__ Cout,
                      const int N)
{
    __shared__ alignas(16) float As[16][68];   // padded: transposed staging
    __shared__ alignas(16) float Bs[16][64];
    const int m0 = blockIdx.x * 64;
    const int n0 = blockIdx.y * 64;
    const int t = threadIdx.x;
    const int am = t >> 2, ak4 = (t & 3) * 4;      // A tile load
    const int lk = t >> 4, ln4 = (t & 15) * 4;     // B tile load
    const int tn4 = (t & 15) * 4, tm4 = (t >> 4) * 4;
    float acc[4][4] = {};

    float bias4[4];
    #pragma unroll
    for (int j = 0; j < 4; ++j)
        bias4[j] = (n0 + tn4 + j < N) ? bias[n0 + tn4 + j] : 0.0f;

    for (int k0 = 0; k0 < CH; k0 += 16) {
        const float4 a4 = *(const float4*)(A + (size_t)(m0 + am)*CH + k0 + ak4);
        float4 bb;
        #pragma unroll
        for (int j = 0; j < 4; ++j) {
            const int nn = n0 + ln4 + j;
            ((float*)&bb)[j] = (nn < N) ? Bw[(size_t)(k0 + lk)*N + nn] : 0.0f;
        }
        #pragma unroll
        for (int j = 0; j < 4; ++j) As[ak4 + j][am] = ((const float*)&a4)[j];
        *(float4*)&Bs[lk][ln4] = bb;
        __syncthreads();
        #pragma unroll
        for (int kk = 0; kk < 16; ++kk) {
            const float4 a = *(const float4*)&As[kk][tm4];
            const float4 bv = *(const float4*)&Bs[kk][tn4];
            #pragma unroll
            for (int i = 0; i < 4; ++i) {
                const float av = ((const float*)&a)[i];
                #pragma unroll
                for (int j = 0; j < 4; ++j) acc[i][j] += av * ((const float*)&bv)[j];
            }
        }
        __syncthreads();
    }
    if (n0 + tn4 < N) {
        #pragma unroll
        for (int i = 0; i < 4; ++i) {
            const int m = m0 + tm4 + i;
            float4 o;
            o.x = acc[i][0] + bias4[0]; o.y = acc[i][1] + bias4[1];
            o.z = acc[i][2] + bias4[2]; o.w = acc[i][3] + bias4[3];
            *(float4*)&Cout[(size_t)m*N + n0 + tn4] = o;
        }
    }
}

// ---------------------------------------------------------------------------
// Deformable sampling: block = 4 positions x 64 lanes; precomputed
// mask-folded bilinear weights + corner offsets in LDS; lane owns 4 channels.
// ---------------------------------------------------------------------------
__global__ __launch_bounds__(256)
void sample_kernel(const float* __restrict__ v,
                   const float* __restrict__ offb,
                   const float* __restrict__ mskb,
                   float* __restrict__ s)
{
    __shared__ alignas(16) float loff[POSB][NOFF];
    __shared__ alignas(16) float lmsk[POSB][NMSK];
    __shared__ alignas(16) float wtab[POSB][GRP*NP][4];
    __shared__ alignas(16) int   itab[POSB][GRP*NP][4];

    const int n0 = blockIdx.x * POSB;
    const int t = threadIdx.x;

    // Phase 1: bulk float4 loads of offsets + masks for 4 positions
    if (t < POSB * (NOFF/4)) {                 // 144 threads
        const int q = t / (NOFF/4), r = t % (NOFF/4);
        *(float4*)&loff[q][r*4] = *(const float4*)&offb[(size_t)(n0+q)*NOFF + r*4];
    } else if (t < POSB * (NOFF/4) + POSB * (NMSK/4)) {   // next 72 threads
        const int u = t - POSB * (NOFF/4);
        const int q = u / (NMSK/4), r = u % (NMSK/4);
        *(float4*)&lmsk[q][r*4] = *(const float4*)&mskb[(size_t)(n0+q)*NMSK + r*4];
    }
    __syncthreads();

    // Phase 2: softmax per (pos, group)
    if (t < POSB * GRP) {
        const int q = t >> 3, g = t & 7;
        float* mm = &lmsk[q][g * NP];
        float mx = -1e30f;
        #pragma unroll
        for (int p = 0; p < NP; ++p) mx = fmaxf(mx, mm[p]);
        float sum = 0.0f;
        #pragma unroll
        for (int p = 0; p < NP; ++p) { const float e = __expf(mm[p] - mx); mm[p] = e; sum += e; }
        const float inv = 1.0f / sum;
        #pragma unroll
        for (int p = 0; p < NP; ++p) mm[p] *= inv;
    }
    __syncthreads();

    // Phase 3: per (pos, g, p) weights (mask & validity folded) + offsets
    for (int u = t; u < POSB * GRP * NP; u += 256) {      // 288 slots
        const int q = u / (GRP*NP), j = u % (GRP*NP);
        const int g = j / NP, p = j % NP;
        const int n = n0 + q;
        const int hw = n % HW;
        const int h = hw / WDIM, w = hw % WDIM;
        const float ox = loff[q][g*18 + p*2 + 0];
        const float oy = loff[q][g*18 + p*2 + 1];
        const float m  = lmsk[q][g*NP + p];
        const float px = (float)(w + p/3) + ox;       // padded coords
        const float py = (float)(h + p%3) + oy;
        const float fx = floorf(px), fy = floorf(py);
        const float wx = px - fx, wy = py - fy;
        const int x0 = (int)fx, y0 = (int)fy;
        const int x1 = x0 + 1, y1 = y0 + 1;
        const float vx0 = (x0 >= 1 && x0 < 57) ? 1.0f : 0.0f;
        const float vx1 = (x1 >= 1 && x1 < 57) ? 1.0f : 0.0f;
        const float vy0 = (y0 >= 1 && y0 < 57) ? 1.0f : 0.0f;
        const float vy1 = (y1 >= 1 && y1 < 57) ? 1.0f : 0.0f;
        const int x0c = min(max(x0, 1), 56), x1c = min(max(x1, 1), 56);
        const int y0c = min(max(y0, 1), 56), y1c = min(max(y1, 1), 56);
        wtab[q][j][0] = m * (1.0f-wx) * (1.0f-wy) * vx0 * vy0;
        wtab[q][j][1] = m * wx        * (1.0f-wy) * vx1 * vy0;
        wtab[q][j][2] = m * (1.0f-wx) * wy        * vx0 * vy1;
        wtab[q][j][3] = m * wx        * wy        * vx1 * vy1;
        itab[q][j][0] = ((y0c-1)*WDIM + (x0c-1)) * CH;
        itab[q][j][1] = ((y0c-1)*WDIM + (x1c-1)) * CH;
        itab[q][j][2] = ((y1c-1)*WDIM + (x0c-1)) * CH;
        itab[q][j][3] = ((y1c-1)*WDIM + (x1c-1)) * CH;
    }
    __syncthreads();

    // Phase 4: accumulation. Wave q handles position n0+q; lane owns 4 ch.
    const int q = t >> 6, lane = t & 63;
    const int n = n0 + q;
    const int b = n / HW;
    const int g = lane >> 3;
    const float* vb = v + (size_t)b*HW*CH + lane*4;
    float4 acc = {0.0f, 0.0f, 0.0f, 0.0f};
    #pragma unroll
    for (int p = 0; p < NP; ++p) {
        const int j = g*NP + p;
        const float4 wv = *(const float4*)&wtab[q][j][0];
        const int4  iv = *(const int4*)&itab[q][j][0];
        const float4 c0 = *(const float4*)(vb + iv.x);
        const float4 c1 = *(const float4*)(vb + iv.y);
        const float4 c2 = *(const float4*)(vb + iv.z);
        const float4 c3 = *(const float4*)(vb + iv.w);
        acc.x += wv.x*c0.x + wv.y*c1.x + wv.z*c2.x + wv.w*c3.x;
        acc.y += wv.x*c0.y + wv.y*c1.y + wv.z*c2.y + wv.w*c3.y;
        acc.z += wv.x*c0.z + wv.y*c1.z + wv.z*c2.z + wv.w*c3.z;
        acc.w += wv.x*c0.w + wv.y*c1.w + wv.z*c2.w + wv.w*c3.w;
    }
    *(float4*)&s[(size_t)n*CH + lane*4] = acc;
}

// ---------------------------------------------------------------------------
// GEMM out: y = SiLU(BN(s @ w_out + b_out)), stored NCHW.
// 128x128 tile, 8x8 micro-tile, m-fast map: NCHW float4 stores along hw.
// ---------------------------------------------------------------------------
__global__ __launch_bounds__(256)
void gemm_out_kernel(const float* __restrict__ A,     // s [MTOT,256]
                     const float* __restrict__ Bw,    // w_out [256,256]
                     const float* __restrict__ bias,  // b_out
                     const float* __restrict__ bn_g,
                     const float* __restrict__ bn_b,
                     const float* __restrict__ bn_mean,
                     const float* __restrict__ bn_var,
                     float* __restrict__ y)           // [B,256,3136]
{
    __shared__ alignas(16) float As[16][128];
    __shared__ alignas(16) float Bs[16][128];
    const int m0 = blockIdx.x * 128;
    const int n0 = blockIdx.y * 128;
    const int t = threadIdx.x;
    const int am  = t >> 1;            // A staging row 0..127
    const int ak8 = (t & 1) * 8;       // A staging k base
    const int lk  = t >> 4;            // B staging k
    const int ln4 = (t & 15) * 4;      // B staging n
    const int tm4 = (t & 15) * 4;      // micro rows base (m-fast)
    const int tn4 = (t >> 4) * 4;      // micro cols base
    float acc[8][8] = {};

    for (int k0 = 0; k0 < CH; k0 += 16) {
        const float4 a0 = *(const float4*)(A + (size_t)(m0 + am) * CH + k0 + ak8);
        const float4 a1 = *(const float4*)(A + (size_t)(m0 + am) * CH + k0 + ak8 + 4);
        const float4 b0 = *(const float4*)(Bw + (size_t)(k0 + lk) * CH + n0 + ln4);
        const float4 b1 = *(const float4*)(Bw + (size_t)(k0 + lk) * CH + n0 + ln4 + 64);
        As[ak8 + 0][am] = a0.x; As[ak8 + 1][am] = a0.y;
        As[ak8 + 2][am] = a0.z; As[ak8 + 3][am] = a0.w;
        As[ak8 + 4][am] = a1.x; As[ak8 + 5][am] = a1.y;
        As[ak8 + 6][am] = a1.z; As[ak8 + 7][am] = a1.w;
        *(float4*)&Bs[lk][ln4]      = b0;
        *(float4*)&Bs[lk][ln4 + 64] = b1;
        __syncthreads();
        #pragma unroll
        for (int kk = 0; kk < 16; ++kk) {
            const float4 aA = *(const float4*)&As[kk][tm4];
            const float4 aB = *(const float4*)&As[kk][tm4 + 64];
            const float4 bA = *(const float4*)&Bs[kk][tn4];
            const float4 bB = *(const float4*)&Bs[kk][tn4 + 64];
            const float av[8] = {aA.x, aA.y, aA.z, aA.w, aB.x, aB.y, aB.z, aB.w};
            const float bv[8] = {bA.x, bA.y, bA.z, bA.w, bB.x, bB.y, bB.z, bB.w};
            #pragma unroll
            for (int i = 0; i < 8; ++i)
                #pragma unroll
                for (int j = 0; j < 8; ++j) acc[i][j] += av[i] * bv[j];
        }
        __syncthreads();
    }
    // rows: m0+tm4+0..3 (i=0..3), m0+64+tm4+0..3 (i=4..7); HW%4==0 -> no straddle
    const int mr0 = m0 + tm4;
    const int mr1 = m0 + 64 + tm4;
    const size_t yo0 = (size_t)(mr0 / HW) * CH * HW + (mr0 % HW);
    const size_t yo1 = (size_t)(mr1 / HW) * CH * HW + (mr1 % HW);
    #pragma unroll
    for (int j = 0; j < 8; ++j) {
        const int nn = n0 + (j < 4 ? tn4 + j : 64 + tn4 + j - 4);
        const float sc = bn_g[nn] * rsqrtf(bn_var[nn] + 1e-5f);
        const float sh = bn_b[nn] - bn_mean[nn] * sc;
        const float bs = bias[nn];
        float4 o0, o1;
        #pragma unroll
        for (int i = 0; i < 4; ++i) {
            float val = (acc[i][j] + bs) * sc + sh;
            ((float*)&o0)[i] = val / (1.0f + expf(-val));   // SiLU
            float val2 = (acc[i + 4][j] + bs) * sc + sh;
            ((float*)&o1)[i] = val2 / (1.0f + expf(-val2));
        }
        *(float4*)&y[yo0 + (size_t)nn * HW] = o0;
        *(float4*)&y[yo1 + (size_t)nn * HW] = o1;
    }
}

extern "C" void kernel_launch(void* const* d_in, const int* in_sizes, int n_in,
                              void* d_out, int out_size, void* d_ws, size_t ws_size,
                              hipStream_t stream) {
    const float* x      = (const float*)d_in[0];
    const float* w_in   = (const float*)d_in[1];
    const float* b_in   = (const float*)d_in[2];
    const float* dw_w   = (const float*)d_in[3];
    const float* dw_b   = (const float*)d_in[4];
    const float* ln_g   = (const float*)d_in[5];
    const float* ln_b   = (const float*)d_in[6];
    const float* w_off  = (const float*)d_in[7];
    const float* b_off  = (const float*)d_in[8];
    const float* w_mask = (const float*)d_in[9];
    const float* b_mask = (const float*)d_in[10];
    const float* w_out  = (const float*)d_in[11];
    const float* b_out  = (const float*)d_in[12];
    const float* bn_g   = (const float*)d_in[13];
    const float* bn_b   = (const float*)d_in[14];
    const float* bn_mean= (const float*)d_in[15];
    const float* bn_var = (const float*)d_in[16];
    float* out = (float*)d_out;

    float* ws   = (float*)d_ws;
    float* v    = ws;                                   // MTOT*CH
    float* f    = v + (size_t)MTOT*CH;                  // MTOT*CH
    float* offb = f + (size_t)MTOT*CH;                  // MTOT*NOFF
    float* mskb = offb + (size_t)MTOT*NOFF;             // MTOT*NMSK
    float* s    = f;                                    // reuse f buffer

    const dim3 blk(256);
    gemm_in_kernel<<<dim3(MTOT/128, CH/128), blk, 0, stream>>>(x, w_in, b_in, v);
    dw_ln_gelu_kernel<<<dim3(HDIM, BATCH), blk, 0, stream>>>(x, dw_w, dw_b, ln_g, ln_b, f);
    gemm_rowA_kernel<<<dim3(MTOT/64, (NOFF + 63)/64), blk, 0, stream>>>(f, w_off, b_off, offb, NOFF);
    gemm_rowA_kernel<<<dim3(MTOT/64, (NMSK + 63)/64), blk, 0, stream>>>(f, w_mask, b_mask, mskb, NMSK);
    sample_kernel<<<dim3(MTOT/POSB), blk, 0, stream>>>(v, offb, mskb, s);
    gemm_out_kernel<<<dim3(MTOT/128, CH/128), blk, 0, stream>>>(s, w_out, b_out, bn_g, bn_b, bn_mean, bn_var, out);
}

// Round 6
// 352.316 us; speedup vs baseline: 1.0753x; 1.0753x over previous
//
#include <hip/hip_runtime.h>
#include <math.h>

// Problem constants
#define BATCH 8
#define CH    256
#define HDIM  56
#define WDIM  56
#define HW    (HDIM*WDIM)          // 3136
#define MTOT  (BATCH*HW)           // 25088
#define GRP   8
#define GC    32
#define NP    9                    // K*K
#define NOFF  (GRP*NP*2)           // 144
#define NMSK  (GRP*NP)             // 72
#define NTOT  (NOFF+NMSK)          // 216
#define POSB  4                    // positions per sample block

// ---------------------------------------------------------------------------
// GEMM 1: v[m][n] = sum_k x[b][k][hw] * w_in[k][n] + b_in[n]
// 128x128 tile, 8x8 micro-tile, register-prefetch double buffering:
// global loads for tile k+1 issue right after the barrier, retire during the
// 16-kk compute (grid is only 392 blocks -> latency must hide via ILP).
// ---------------------------------------------------------------------------
__global__ __launch_bounds__(256)
void gemm_in_kernel(const float* __restrict__ x,
                    const float* __restrict__ w_in,
                    const float* __restrict__ b_in,
                    float* __restrict__ v)
{
    __shared__ alignas(16) float As[16][128];
    __shared__ alignas(16) float Bs[16][128];
    const int m0 = blockIdx.x * 128;
    const int n0 = blockIdx.y * 128;
    const int t = threadIdx.x;
    const int lk  = t >> 4;            // staging k 0..15
    const int lm4 = (t & 15) * 4;      // staging m/n 0..60
    const int tm4 = (t >> 4) * 4;      // micro rows base
    const int tn4 = (t & 15) * 4;      // micro cols base
    float acc[8][8] = {};

    // batch-safe A chunk bases (HW%4==0 -> a float4 chunk never crosses batch)
    const int mA0 = m0 + lm4, mA1 = m0 + lm4 + 64;
    const size_t aoff0 = (size_t)(mA0 / HW) * CH * HW + (mA0 % HW);
    const size_t aoff1 = (size_t)(mA1 / HW) * CH * HW + (mA1 % HW);

    float4 pa0 = *(const float4*)(x + aoff0 + (size_t)lk * HW);
    float4 pa1 = *(const float4*)(x + aoff1 + (size_t)lk * HW);
    float4 pb0 = *(const float4*)(w_in + (size_t)lk * CH + n0 + lm4);
    float4 pb1 = *(const float4*)(w_in + (size_t)lk * CH + n0 + lm4 + 64);

    for (int k0 = 0; k0 < CH; k0 += 16) {
        *(float4*)&As[lk][lm4]      = pa0;
        *(float4*)&As[lk][lm4 + 64] = pa1;
        *(float4*)&Bs[lk][lm4]      = pb0;
        *(float4*)&Bs[lk][lm4 + 64] = pb1;
        __syncthreads();
        if (k0 + 16 < CH) {
            const int k = k0 + 16 + lk;
            pa0 = *(const float4*)(x + aoff0 + (size_t)k * HW);
            pa1 = *(const float4*)(x + aoff1 + (size_t)k * HW);
            pb0 = *(const float4*)(w_in + (size_t)k * CH + n0 + lm4);
            pb1 = *(const float4*)(w_in + (size_t)k * CH + n0 + lm4 + 64);
        }
        #pragma unroll
        for (int kk = 0; kk < 16; ++kk) {
            const float4 aA = *(const float4*)&As[kk][tm4];
            const float4 aB = *(const float4*)&As[kk][tm4 + 64];
            const float4 bA = *(const float4*)&Bs[kk][tn4];
            const float4 bB = *(const float4*)&Bs[kk][tn4 + 64];
            const float av[8] = {aA.x, aA.y, aA.z, aA.w, aB.x, aB.y, aB.z, aB.w};
            const float bv[8] = {bA.x, bA.y, bA.z, bA.w, bB.x, bB.y, bB.z, bB.w};
            #pragma unroll
            for (int i = 0; i < 8; ++i)
                #pragma unroll
                for (int j = 0; j < 8; ++j) acc[i][j] += av[i] * bv[j];
        }
        __syncthreads();
    }
    const float4 biasA = *(const float4*)&b_in[n0 + tn4];
    const float4 biasB = *(const float4*)&b_in[n0 + tn4 + 64];
    #pragma unroll
    for (int i = 0; i < 8; ++i) {
        const int m = m0 + (i < 4 ? tm4 + i : 64 + tm4 + i - 4);
        float4 o0, o1;
        o0.x = acc[i][0] + biasA.x; o0.y = acc[i][1] + biasA.y;
        o0.z = acc[i][2] + biasA.z; o0.w = acc[i][3] + biasA.w;
        o1.x = acc[i][4] + biasB.x; o1.y = acc[i][5] + biasB.y;
        o1.z = acc[i][6] + biasB.z; o1.w = acc[i][7] + biasB.w;
        *(float4*)&v[(size_t)m * CH + n0 + tn4]      = o0;
        *(float4*)&v[(size_t)m * CH + n0 + tn4 + 64] = o1;
    }
}

// ---------------------------------------------------------------------------
// Fused depthwise 3x3 + bias + LayerNorm(C) + exact GELU -> f (NHWC)
// ---------------------------------------------------------------------------
__global__ __launch_bounds__(256)
void dw_ln_gelu_kernel(const float* __restrict__ x,
                       const float* __restrict__ dw_w,
                       const float* __restrict__ dw_b,
                       const float* __restrict__ ln_g,
                       const float* __restrict__ ln_b,
                       float* __restrict__ f)
{
    __shared__ float tile[WDIM][CH + 1];    // 56 x 257 floats (57.5 KB)
    __shared__ float red1[WDIM][4], red2[WDIM][4];
    __shared__ float meanA[WDIM], rstdA[WDIM];

    const int h = blockIdx.x;
    const int b = blockIdx.y;
    const int t = threadIdx.x;
    const int lane = t & 63;
    const int wv   = t >> 6;               // wave id 0..3

    // ---- Phase 1: depthwise conv, 4 channels (one per wave) per iteration
    for (int cg = 0; cg < CH / 4; ++cg) {
        const int c = cg * 4 + wv;
        const float* xp = x + ((size_t)b * CH + c) * HW;
        float rowv[3];
        #pragma unroll
        for (int r = 0; r < 3; ++r) {
            const int hh = h + r - 1;
            rowv[r] = (lane < WDIM && hh >= 0 && hh < HDIM) ? xp[hh * WDIM + lane] : 0.0f;
        }
        const float* wp = dw_w + c * 9;     // wave-uniform -> scalar loads
        float acc = dw_b[c];
        #pragma unroll
        for (int r = 0; r < 3; ++r) {
            float L = __shfl_up(rowv[r], 1);
            float R = __shfl_down(rowv[r], 1);
            if (lane == 0) L = 0.0f;
            acc += L * wp[r * 3 + 0] + rowv[r] * wp[r * 3 + 1] + R * wp[r * 3 + 2];
        }
        if (lane < WDIM)
            tile[lane][c] = acc;
    }
    __syncthreads();

    // ---- Phase 2: LN statistics per position
    if (t < 224) {
        const int p = t >> 2, q = t & 3;
        float s1 = 0.0f, s2 = 0.0f;
        #pragma unroll 8
        for (int i = 0; i < 64; ++i) {
            const float v = tile[p][q * 64 + i];
            s1 += v; s2 += v * v;
        }
        red1[p][q] = s1; red2[p][q] = s2;
    }
    __syncthreads();
    if (t < WDIM) {
        const float s1 = red1[t][0] + red1[t][1] + red1[t][2] + red1[t][3];
        const float s2 = red2[t][0] + red2[t][1] + red2[t][2] + red2[t][3];
        const float m = s1 * (1.0f / 256.0f);
        const float var = s2 * (1.0f / 256.0f) - m * m;
        meanA[t] = m;
        rstdA[t] = rsqrtf(var + 1e-5f);
    }
    __syncthreads();

    // ---- Phase 3: normalize + GELU + coalesced NHWC store
    const float gam = ln_g[t], bet = ln_b[t];
    const size_t n0 = (size_t)(b * HDIM + h) * WDIM;
    for (int p = 0; p < WDIM; ++p) {
        const float xn = (tile[p][t] - meanA[p]) * rstdA[p] * gam + bet;
        const float g = 0.5f * xn * (1.0f + erff(xn * 0.70710678118654752f));
        f[(n0 + p) * CH + t] = g;
    }
}

// ---------------------------------------------------------------------------
// Fused offset+mask GEMM: Cvirt[m][n] = f[m][:] @ [w_off | w_mask][:, n],
// n in [0,216). 128-thread blocks, 128x64 tile, 8x8 micro-tile,
// register-prefetch double buffering. 144%4==0 -> float4 chunks never
// straddle the off/mask boundary.
// ---------------------------------------------------------------------------
__global__ __launch_bounds__(128)
void gemm_offmask_kernel(const float* __restrict__ A,      // f [MTOT,256]
                         const float* __restrict__ w_off,  // [256,144]
                         const float* __restrict__ b_off,
                         const float* __restrict__ w_mask, // [256,72]
                         const float* __restrict__ b_mask,
                         float* __restrict__ offb,         // [MTOT,144]
                         float* __restrict__ mskb)         // [MTOT,72]
{
    __shared__ alignas(16) float As[16][128];
    __shared__ alignas(16) float Bs[16][64];
    const int m0 = blockIdx.x * 128;
    const int n0 = blockIdx.y * 64;
    const int t = threadIdx.x;          // 0..127
    const int bkk = t & 15;             // B staging k row
    const int bc  = n0 + (t >> 4) * 8;  // B staging col base (global, 2 chunks)
    const int tm8 = (t & 15) * 8;       // micro rows base
    const int tn8 = (t >> 4) * 8;       // micro cols base
    float acc[8][8] = {};

    const float* arow = A + (size_t)(m0 + t) * CH;

    auto ldb = [&](int k, int cc) -> float4 {
        if (cc < NOFF) return *(const float4*)&w_off[(size_t)k * NOFF + cc];
        if (cc < NTOT) return *(const float4*)&w_mask[(size_t)k * NMSK + (cc - NOFF)];
        return float4{0.0f, 0.0f, 0.0f, 0.0f};
    };

    float4 pa[4];
    #pragma unroll
    for (int u = 0; u < 4; ++u) pa[u] = *(const float4*)(arow + u * 4);
    float4 pb0 = ldb(bkk, bc);
    float4 pb1 = ldb(bkk, bc + 4);

    for (int k0 = 0; k0 < CH; k0 += 16) {
        #pragma unroll
        for (int u = 0; u < 4; ++u) {
            As[u*4 + 0][t] = pa[u].x;
            As[u*4 + 1][t] = pa[u].y;
            As[u*4 + 2][t] = pa[u].z;
            As[u*4 + 3][t] = pa[u].w;
        }
        *(float4*)&Bs[bkk][(t >> 4) * 8]     = pb0;
        *(float4*)&Bs[bkk][(t >> 4) * 8 + 4] = pb1;
        __syncthreads();
        if (k0 + 16 < CH) {
            #pragma unroll
            for (int u = 0; u < 4; ++u)
                pa[u] = *(const float4*)(arow + k0 + 16 + u * 4);
            pb0 = ldb(k0 + 16 + bkk, bc);
            pb1 = ldb(k0 + 16 + bkk, bc + 4);
        }
        #pragma unroll
        for (int kk = 0; kk < 16; ++kk) {
            const float4 aA = *(const float4*)&As[kk][tm8];
            const float4 aB = *(const float4*)&As[kk][tm8 + 4];
            const float4 bA = *(const float4*)&Bs[kk][tn8];
            const float4 bB = *(const float4*)&Bs[kk][tn8 + 4];
            const float av[8] = {aA.x, aA.y, aA.z, aA.w, aB.x, aB.y, aB.z, aB.w};
            const float bv[8] = {bA.x, bA.y, bA.z, bA.w, bB.x, bB.y, bB.z, bB.w};
            #pragma unroll
            for (int i = 0; i < 8; ++i)
                #pragma unroll
                for (int j = 0; j < 8; ++j) acc[i][j] += av[i] * bv[j];
        }
        __syncthreads();
    }

    auto ldbias = [&](int cc) -> float4 {
        if (cc < NOFF) return *(const float4*)&b_off[cc];
        if (cc < NTOT) return *(const float4*)&b_mask[cc - NOFF];
        return float4{0.0f, 0.0f, 0.0f, 0.0f};
    };
    const int c0 = n0 + tn8;
    const int c1 = c0 + 4;
    const float4 bs0 = ldbias(c0);
    const float4 bs1 = ldbias(c1);
    #pragma unroll
    for (int i = 0; i < 8; ++i) {
        const int m = m0 + tm8 + i;
        float4 o0, o1;
        o0.x = acc[i][0] + bs0.x; o0.y = acc[i][1] + bs0.y;
        o0.z = acc[i][2] + bs0.z; o0.w = acc[i][3] + bs0.w;
        o1.x = acc[i][4] + bs1.x; o1.y = acc[i][5] + bs1.y;
        o1.z = acc[i][6] + bs1.z; o1.w = acc[i][7] + bs1.w;
        if (c0 < NOFF)      *(float4*)&offb[(size_t)m * NOFF + c0] = o0;
        else if (c0 < NTOT) *(float4*)&mskb[(size_t)m * NMSK + (c0 - NOFF)] = o0;
        if (c1 < NOFF)      *(float4*)&offb[(size_t)m * NOFF + c1] = o1;
        else if (c1 < NTOT) *(float4*)&mskb[(size_t)m * NMSK + (c1 - NOFF)] = o1;
    }
}

// ---------------------------------------------------------------------------
// Deformable sampling: block = 4 positions x 64 lanes; precomputed
// mask-folded bilinear weights + corner offsets in LDS; lane owns 4 channels.
// ---------------------------------------------------------------------------
__global__ __launch_bounds__(256)
void sample_kernel(const float* __restrict__ v,
                   const float* __restrict__ offb,
                   const float* __restrict__ mskb,
                   float* __restrict__ s)
{
    __shared__ alignas(16) float loff[POSB][NOFF];
    __shared__ alignas(16) float lmsk[POSB][NMSK];
    __shared__ alignas(16) float wtab[POSB][GRP*NP][4];
    __shared__ alignas(16) int   itab[POSB][GRP*NP][4];

    const int n0 = blockIdx.x * POSB;
    const int t = threadIdx.x;

    // Phase 1: bulk float4 loads of offsets + masks for 4 positions
    if (t < POSB * (NOFF/4)) {                 // 144 threads
        const int q = t / (NOFF/4), r = t % (NOFF/4);
        *(float4*)&loff[q][r*4] = *(const float4*)&offb[(size_t)(n0+q)*NOFF + r*4];
    } else if (t < POSB * (NOFF/4) + POSB * (NMSK/4)) {   // next 72 threads
        const int u = t - POSB * (NOFF/4);
        const int q = u / (NMSK/4), r = u % (NMSK/4);
        *(float4*)&lmsk[q][r*4] = *(const float4*)&mskb[(size_t)(n0+q)*NMSK + r*4];
    }
    __syncthreads();

    // Phase 2: softmax per (pos, group)
    if (t < POSB * GRP) {
        const int q = t >> 3, g = t & 7;
        float* mm = &lmsk[q][g * NP];
        float mx = -1e30f;
        #pragma unroll
        for (int p = 0; p < NP; ++p) mx = fmaxf(mx, mm[p]);
        float sum = 0.0f;
        #pragma unroll
        for (int p = 0; p < NP; ++p) { const float e = __expf(mm[p] - mx); mm[p] = e; sum += e; }
        const float inv = 1.0f / sum;
        #pragma unroll
        for (int p = 0; p < NP; ++p) mm[p] *= inv;
    }
    __syncthreads();

    // Phase 3: per (pos, g, p) weights (mask & validity folded) + offsets
    for (int u = t; u < POSB * GRP * NP; u += 256) {      // 288 slots
        const int q = u / (GRP*NP), j = u % (GRP*NP);
        const int g = j / NP, p = j % NP;
        const int n = n0 + q;
        const int hw = n % HW;
        const int h = hw / WDIM, w = hw % WDIM;
        const float ox = loff[q][g*18 + p*2 + 0];
        const float oy = loff[q][g*18 + p*2 + 1];
        const float m  = lmsk[q][g*NP + p];
        const float px = (float)(w + p/3) + ox;       // padded coords
        const float py = (float)(h + p%3) + oy;
        const float fx = floorf(px), fy = floorf(py);
        const float wx = px - fx, wy = py - fy;
        const int x0 = (int)fx, y0 = (int)fy;
        const int x1 = x0 + 1, y1 = y0 + 1;
        const float vx0 = (x0 >= 1 && x0 < 57) ? 1.0f : 0.0f;
        const float vx1 = (x1 >= 1 && x1 < 57) ? 1.0f : 0.0f;
        const float vy0 = (y0 >= 1 && y0 < 57) ? 1.0f : 0.0f;
        const float vy1 = (y1 >= 1 && y1 < 57) ? 1.0f : 0.0f;
        const int x0c = min(max(x0, 1), 56), x1c = min(max(x1, 1), 56);
        const int y0c = min(max(y0, 1), 56), y1c = min(max(y1, 1), 56);
        wtab[q][j][0] = m * (1.0f-wx) * (1.0f-wy) * vx0 * vy0;
        wtab[q][j][1] = m * wx        * (1.0f-wy) * vx1 * vy0;
        wtab[q][j][2] = m * (1.0f-wx) * wy        * vx0 * vy1;
        wtab[q][j][3] = m * wx        * wy        * vx1 * vy1;
        itab[q][j][0] = ((y0c-1)*WDIM + (x0c-1)) * CH;
        itab[q][j][1] = ((y0c-1)*WDIM + (x1c-1)) * CH;
        itab[q][j][2] = ((y1c-1)*WDIM + (x0c-1)) * CH;
        itab[q][j][3] = ((y1c-1)*WDIM + (x1c-1)) * CH;
    }
    __syncthreads();

    // Phase 4: accumulation. Wave q handles position n0+q; lane owns 4 ch.
    const int q = t >> 6, lane = t & 63;
    const int n = n0 + q;
    const int b = n / HW;
    const int g = lane >> 3;
    const float* vb = v + (size_t)b*HW*CH + lane*4;
    float4 acc = {0.0f, 0.0f, 0.0f, 0.0f};
    #pragma unroll
    for (int p = 0; p < NP; ++p) {
        const int j = g*NP + p;
        const float4 wv = *(const float4*)&wtab[q][j][0];
        const int4  iv = *(const int4*)&itab[q][j][0];
        const float4 c0 = *(const float4*)(vb + iv.x);
        const float4 c1 = *(const float4*)(vb + iv.y);
        const float4 c2 = *(const float4*)(vb + iv.z);
        const float4 c3 = *(const float4*)(vb + iv.w);
        acc.x += wv.x*c0.x + wv.y*c1.x + wv.z*c2.x + wv.w*c3.x;
        acc.y += wv.x*c0.y + wv.y*c1.y + wv.z*c2.y + wv.w*c3.y;
        acc.z += wv.x*c0.z + wv.y*c1.z + wv.z*c2.z + wv.w*c3.z;
        acc.w += wv.x*c0.w + wv.y*c1.w + wv.z*c2.w + wv.w*c3.w;
    }
    *(float4*)&s[(size_t)n*CH + lane*4] = acc;
}

// ---------------------------------------------------------------------------
// GEMM out: y = SiLU(BN(s @ w_out + b_out)), stored NCHW.
// 128x128 tile, 8x8 micro-tile, m-fast map, register-prefetch.
// ---------------------------------------------------------------------------
__global__ __launch_bounds__(256)
void gemm_out_kernel(const float* __restrict__ A,     // s [MTOT,256]
                     const float* __restrict__ Bw,    // w_out [256,256]
                     const float* __restrict__ bias,  // b_out
                     const float* __restrict__ bn_g,
                     const float* __restrict__ bn_b,
                     const float* __restrict__ bn_mean,
                     const float* __restrict__ bn_var,
                     float* __restrict__ y)           // [B,256,3136]
{
    __shared__ alignas(16) float As[16][128];
    __shared__ alignas(16) float Bs[16][128];
    const int m0 = blockIdx.x * 128;
    const int n0 = blockIdx.y * 128;
    const int t = threadIdx.x;
    const int am  = t >> 1;            // A staging row 0..127
    const int ak8 = (t & 1) * 8;       // A staging k base
    const int lk  = t >> 4;            // B staging k
    const int ln4 = (t & 15) * 4;      // B staging n
    const int tm4 = (t & 15) * 4;      // micro rows base (m-fast)
    const int tn4 = (t >> 4) * 4;      // micro cols base
    float acc[8][8] = {};

    const float* arow = A + (size_t)(m0 + am) * CH;
    float4 pa0 = *(const float4*)(arow + ak8);
    float4 pa1 = *(const float4*)(arow + ak8 + 4);
    float4 pb0 = *(const float4*)(Bw + (size_t)lk * CH + n0 + ln4);
    float4 pb1 = *(const float4*)(Bw + (size_t)lk * CH + n0 + ln4 + 64);

    for (int k0 = 0; k0 < CH; k0 += 16) {
        As[ak8 + 0][am] = pa0.x; As[ak8 + 1][am] = pa0.y;
        As[ak8 + 2][am] = pa0.z; As[ak8 + 3][am] = pa0.w;
        As[ak8 + 4][am] = pa1.x; As[ak8 + 5][am] = pa1.y;
        As[ak8 + 6][am] = pa1.z; As[ak8 + 7][am] = pa1.w;
        *(float4*)&Bs[lk][ln4]      = pb0;
        *(float4*)&Bs[lk][ln4 + 64] = pb1;
        __syncthreads();
        if (k0 + 16 < CH) {
            pa0 = *(const float4*)(arow + k0 + 16 + ak8);
            pa1 = *(const float4*)(arow + k0 + 16 + ak8 + 4);
            pb0 = *(const float4*)(Bw + (size_t)(k0 + 16 + lk) * CH + n0 + ln4);
            pb1 = *(const float4*)(Bw + (size_t)(k0 + 16 + lk) * CH + n0 + ln4 + 64);
        }
        #pragma unroll
        for (int kk = 0; kk < 16; ++kk) {
            const float4 aA = *(const float4*)&As[kk][tm4];
            const float4 aB = *(const float4*)&As[kk][tm4 + 64];
            const float4 bA = *(const float4*)&Bs[kk][tn4];
            const float4 bB = *(const float4*)&Bs[kk][tn4 + 64];
            const float av[8] = {aA.x, aA.y, aA.z, aA.w, aB.x, aB.y, aB.z, aB.w};
            const float bv[8] = {bA.x, bA.y, bA.z, bA.w, bB.x, bB.y, bB.z, bB.w};
            #pragma unroll
            for (int i = 0; i < 8; ++i)
                #pragma unroll
                for (int j = 0; j < 8; ++j) acc[i][j] += av[i] * bv[j];
        }
        __syncthreads();
    }
    // rows: m0+tm4+0..3 (i=0..3), m0+64+tm4+0..3 (i=4..7); HW%4==0 -> no straddle
    const int mr0 = m0 + tm4;
    const int mr1 = m0 + 64 + tm4;
    const size_t yo0 = (size_t)(mr0 / HW) * CH * HW + (mr0 % HW);
    const size_t yo1 = (size_t)(mr1 / HW) * CH * HW + (mr1 % HW);
    #pragma unroll
    for (int j = 0; j < 8; ++j) {
        const int nn = n0 + (j < 4 ? tn4 + j : 64 + tn4 + j - 4);
        const float sc = bn_g[nn] * rsqrtf(bn_var[nn] + 1e-5f);
        const float sh = bn_b[nn] - bn_mean[nn] * sc;
        const float bs = bias[nn];
        float4 o0, o1;
        #pragma unroll
        for (int i = 0; i < 4; ++i) {
            float val = (acc[i][j] + bs) * sc + sh;
            ((float*)&o0)[i] = val / (1.0f + expf(-val));   // SiLU
            float val2 = (acc[i + 4][j] + bs) * sc + sh;
            ((float*)&o1)[i] = val2 / (1.0f + expf(-val2));
        }
        *(float4*)&y[yo0 + (size_t)nn * HW] = o0;
        *(float4*)&y[yo1 + (size_t)nn * HW] = o1;
    }
}

extern "C" void kernel_launch(void* const* d_in, const int* in_sizes, int n_in,
                              void* d_out, int out_size, void* d_ws, size_t ws_size,
                              hipStream_t stream) {
    const float* x      = (const float*)d_in[0];
    const float* w_in   = (const float*)d_in[1];
    const float* b_in   = (const float*)d_in[2];
    const float* dw_w   = (const float*)d_in[3];
    const float* dw_b   = (const float*)d_in[4];
    const float* ln_g   = (const float*)d_in[5];
    const float* ln_b   = (const float*)d_in[6];
    const float* w_off  = (const float*)d_in[7];
    const float* b_off  = (const float*)d_in[8];
    const float* w_mask = (const float*)d_in[9];
    const float* b_mask = (const float*)d_in[10];
    const float* w_out  = (const float*)d_in[11];
    const float* b_out  = (const float*)d_in[12];
    const float* bn_g   = (const float*)d_in[13];
    const float* bn_b   = (const float*)d_in[14];
    const float* bn_mean= (const float*)d_in[15];
    const float* bn_var = (const float*)d_in[16];
    float* out = (float*)d_out;

    float* ws   = (float*)d_ws;
    float* v    = ws;                                   // MTOT*CH
    float* f    = v + (size_t)MTOT*CH;                  // MTOT*CH
    float* offb = f + (size_t)MTOT*CH;                  // MTOT*NOFF
    float* mskb = offb + (size_t)MTOT*NOFF;             // MTOT*NMSK
    float* s    = f;                                    // reuse f buffer

    gemm_in_kernel<<<dim3(MTOT/128, CH/128), dim3(256), 0, stream>>>(x, w_in, b_in, v);
    dw_ln_gelu_kernel<<<dim3(HDIM, BATCH), dim3(256), 0, stream>>>(x, dw_w, dw_b, ln_g, ln_b, f);
    gemm_offmask_kernel<<<dim3(MTOT/128, (NTOT + 63)/64), dim3(128), 0, stream>>>(
        f, w_off, b_off, w_mask, b_mask, offb, mskb);
    sample_kernel<<<dim3(MTOT/POSB), dim3(256), 0, stream>>>(v, offb, mskb, s);
    gemm_out_kernel<<<dim3(MTOT/128, CH/128), dim3(256), 0, stream>>>(s, w_out, b_out, bn_g, bn_b, bn_mean, bn_var, out);
}

// Round 7
// 351.227 us; speedup vs baseline: 1.0786x; 1.0031x over previous
//
#include <hip/hip_runtime.h>
#include <math.h>

// Problem constants
#define BATCH 8
#define CH    256
#define HDIM  56
#define WDIM  56
#define HW    (HDIM*WDIM)          // 3136
#define MTOT  (BATCH*HW)           // 25088
#define GRP   8
#define GC    32
#define NP    9                    // K*K
#define NOFF  (GRP*NP*2)           // 144
#define NMSK  (GRP*NP)             // 72
#define NTOT  (NOFF+NMSK)          // 216
#define POSB  4                    // positions per sample block

// ---------------------------------------------------------------------------
// GEMM 1: v[m][n] = sum_k x[b][k][hw] * w_in[k][n] + b_in[n]
// 128x128 tile, 8x8 micro-tile, register-prefetch double buffering.
// ---------------------------------------------------------------------------
__global__ __launch_bounds__(256)
void gemm_in_kernel(const float* __restrict__ x,
                    const float* __restrict__ w_in,
                    const float* __restrict__ b_in,
                    float* __restrict__ v)
{
    __shared__ alignas(16) float As[16][128];
    __shared__ alignas(16) float Bs[16][128];
    const int m0 = blockIdx.x * 128;
    const int n0 = blockIdx.y * 128;
    const int t = threadIdx.x;
    const int lk  = t >> 4;            // staging k 0..15
    const int lm4 = (t & 15) * 4;      // staging m/n 0..60
    const int tm4 = (t >> 4) * 4;      // micro rows base
    const int tn4 = (t & 15) * 4;      // micro cols base
    float acc[8][8] = {};

    // batch-safe A chunk bases (HW%4==0 -> a float4 chunk never crosses batch)
    const int mA0 = m0 + lm4, mA1 = m0 + lm4 + 64;
    const size_t aoff0 = (size_t)(mA0 / HW) * CH * HW + (mA0 % HW);
    const size_t aoff1 = (size_t)(mA1 / HW) * CH * HW + (mA1 % HW);

    float4 pa0 = *(const float4*)(x + aoff0 + (size_t)lk * HW);
    float4 pa1 = *(const float4*)(x + aoff1 + (size_t)lk * HW);
    float4 pb0 = *(const float4*)(w_in + (size_t)lk * CH + n0 + lm4);
    float4 pb1 = *(const float4*)(w_in + (size_t)lk * CH + n0 + lm4 + 64);

    for (int k0 = 0; k0 < CH; k0 += 16) {
        *(float4*)&As[lk][lm4]      = pa0;
        *(float4*)&As[lk][lm4 + 64] = pa1;
        *(float4*)&Bs[lk][lm4]      = pb0;
        *(float4*)&Bs[lk][lm4 + 64] = pb1;
        __syncthreads();
        if (k0 + 16 < CH) {
            const int k = k0 + 16 + lk;
            pa0 = *(const float4*)(x + aoff0 + (size_t)k * HW);
            pa1 = *(const float4*)(x + aoff1 + (size_t)k * HW);
            pb0 = *(const float4*)(w_in + (size_t)k * CH + n0 + lm4);
            pb1 = *(const float4*)(w_in + (size_t)k * CH + n0 + lm4 + 64);
        }
        #pragma unroll
        for (int kk = 0; kk < 16; ++kk) {
            const float4 aA = *(const float4*)&As[kk][tm4];
            const float4 aB = *(const float4*)&As[kk][tm4 + 64];
            const float4 bA = *(const float4*)&Bs[kk][tn4];
            const float4 bB = *(const float4*)&Bs[kk][tn4 + 64];
            const float av[8] = {aA.x, aA.y, aA.z, aA.w, aB.x, aB.y, aB.z, aB.w};
            const float bv[8] = {bA.x, bA.y, bA.z, bA.w, bB.x, bB.y, bB.z, bB.w};
            #pragma unroll
            for (int i = 0; i < 8; ++i)
                #pragma unroll
                for (int j = 0; j < 8; ++j) acc[i][j] += av[i] * bv[j];
        }
        __syncthreads();
    }
    const float4 biasA = *(const float4*)&b_in[n0 + tn4];
    const float4 biasB = *(const float4*)&b_in[n0 + tn4 + 64];
    #pragma unroll
    for (int i = 0; i < 8; ++i) {
        const int m = m0 + (i < 4 ? tm4 + i : 64 + tm4 + i - 4);
        float4 o0, o1;
        o0.x = acc[i][0] + biasA.x; o0.y = acc[i][1] + biasA.y;
        o0.z = acc[i][2] + biasA.z; o0.w = acc[i][3] + biasA.w;
        o1.x = acc[i][4] + biasB.x; o1.y = acc[i][5] + biasB.y;
        o1.z = acc[i][6] + biasB.z; o1.w = acc[i][7] + biasB.w;
        *(float4*)&v[(size_t)m * CH + n0 + tn4]      = o0;
        *(float4*)&v[(size_t)m * CH + n0 + tn4 + 64] = o1;
    }
}

// ---------------------------------------------------------------------------
// Fused depthwise 3x3 + bias + LayerNorm(C) + exact GELU -> f (NHWC)
// ---------------------------------------------------------------------------
__global__ __launch_bounds__(256)
void dw_ln_gelu_kernel(const float* __restrict__ x,
                       const float* __restrict__ dw_w,
                       const float* __restrict__ dw_b,
                       const float* __restrict__ ln_g,
                       const float* __restrict__ ln_b,
                       float* __restrict__ f)
{
    __shared__ float tile[WDIM][CH + 1];    // 56 x 257 floats (57.5 KB)
    __shared__ float red1[WDIM][4], red2[WDIM][4];
    __shared__ float meanA[WDIM], rstdA[WDIM];

    const int h = blockIdx.x;
    const int b = blockIdx.y;
    const int t = threadIdx.x;
    const int lane = t & 63;
    const int wv   = t >> 6;               // wave id 0..3

    // ---- Phase 1: depthwise conv, 4 channels (one per wave) per iteration
    for (int cg = 0; cg < CH / 4; ++cg) {
        const int c = cg * 4 + wv;
        const float* xp = x + ((size_t)b * CH + c) * HW;
        float rowv[3];
        #pragma unroll
        for (int r = 0; r < 3; ++r) {
            const int hh = h + r - 1;
            rowv[r] = (lane < WDIM && hh >= 0 && hh < HDIM) ? xp[hh * WDIM + lane] : 0.0f;
        }
        const float* wp = dw_w + c * 9;     // wave-uniform -> scalar loads
        float acc = dw_b[c];
        #pragma unroll
        for (int r = 0; r < 3; ++r) {
            float L = __shfl_up(rowv[r], 1);
            float R = __shfl_down(rowv[r], 1);
            if (lane == 0) L = 0.0f;
            acc += L * wp[r * 3 + 0] + rowv[r] * wp[r * 3 + 1] + R * wp[r * 3 + 2];
        }
        if (lane < WDIM)
            tile[lane][c] = acc;
    }
    __syncthreads();

    // ---- Phase 2: LN statistics per position
    if (t < 224) {
        const int p = t >> 2, q = t & 3;
        float s1 = 0.0f, s2 = 0.0f;
        #pragma unroll 8
        for (int i = 0; i < 64; ++i) {
            const float v = tile[p][q * 64 + i];
            s1 += v; s2 += v * v;
        }
        red1[p][q] = s1; red2[p][q] = s2;
    }
    __syncthreads();
    if (t < WDIM) {
        const float s1 = red1[t][0] + red1[t][1] + red1[t][2] + red1[t][3];
        const float s2 = red2[t][0] + red2[t][1] + red2[t][2] + red2[t][3];
        const float m = s1 * (1.0f / 256.0f);
        const float var = s2 * (1.0f / 256.0f) - m * m;
        meanA[t] = m;
        rstdA[t] = rsqrtf(var + 1e-5f);
    }
    __syncthreads();

    // ---- Phase 3: normalize + GELU + coalesced NHWC store
    const float gam = ln_g[t], bet = ln_b[t];
    const size_t n0 = (size_t)(b * HDIM + h) * WDIM;
    for (int p = 0; p < WDIM; ++p) {
        const float xn = (tile[p][t] - meanA[p]) * rstdA[p] * gam + bet;
        const float g = 0.5f * xn * (1.0f + erff(xn * 0.70710678118654752f));
        f[(n0 + p) * CH + t] = g;
    }
}

// ---------------------------------------------------------------------------
// Fused offset+mask GEMM: Cvirt[m][n] = f[m][:] @ [w_off | w_mask][:, n],
// n in [0,216). 128-thread blocks, 128x64 tile, 8x8 micro-tile with
// conflict-free split mapping: rows {tm4,tm4+64}, cols {tn4,tn4+32}.
// blockIdx.x = n-tile so blocks sharing an A-tile are dispatch-adjacent.
// ---------------------------------------------------------------------------
__global__ __launch_bounds__(128)
void gemm_offmask_kernel(const float* __restrict__ A,      // f [MTOT,256]
                         const float* __restrict__ w_off,  // [256,144]
                         const float* __restrict__ b_off,
                         const float* __restrict__ w_mask, // [256,72]
                         const float* __restrict__ b_mask,
                         float* __restrict__ offb,         // [MTOT,144]
                         float* __restrict__ mskb)         // [MTOT,72]
{
    __shared__ alignas(16) float As[16][128];
    __shared__ alignas(16) float Bs[16][64];
    const int n0 = blockIdx.x * 64;
    const int m0 = blockIdx.y * 128;
    const int t = threadIdx.x;          // 0..127
    const int bkk = t & 15;             // B staging k row
    const int bc  = n0 + (t >> 4) * 8;  // B staging col base (global, 2 chunks)
    const int tm4 = (t & 15) * 4;       // micro rows base (split {0,64})
    const int tn4 = (t >> 4) * 4;       // micro cols base (split {0,32})
    float acc[8][8] = {};               // [row i: {tm4,+64}][col j: {tn4,+32}]

    const float* arow = A + (size_t)(m0 + t) * CH;

    auto ldb = [&](int k, int cc) -> float4 {
        if (cc < NOFF) return *(const float4*)&w_off[(size_t)k * NOFF + cc];
        if (cc < NTOT) return *(const float4*)&w_mask[(size_t)k * NMSK + (cc - NOFF)];
        return float4{0.0f, 0.0f, 0.0f, 0.0f};
    };

    float4 pa[4];
    #pragma unroll
    for (int u = 0; u < 4; ++u) pa[u] = *(const float4*)(arow + u * 4);
    float4 pb0 = ldb(bkk, bc);
    float4 pb1 = ldb(bkk, bc + 4);

    for (int k0 = 0; k0 < CH; k0 += 16) {
        #pragma unroll
        for (int u = 0; u < 4; ++u) {
            As[u*4 + 0][t] = pa[u].x;
            As[u*4 + 1][t] = pa[u].y;
            As[u*4 + 2][t] = pa[u].z;
            As[u*4 + 3][t] = pa[u].w;
        }
        *(float4*)&Bs[bkk][(t >> 4) * 8]     = pb0;
        *(float4*)&Bs[bkk][(t >> 4) * 8 + 4] = pb1;
        __syncthreads();
        if (k0 + 16 < CH) {
            #pragma unroll
            for (int u = 0; u < 4; ++u)
                pa[u] = *(const float4*)(arow + k0 + 16 + u * 4);
            pb0 = ldb(k0 + 16 + bkk, bc);
            pb1 = ldb(k0 + 16 + bkk, bc + 4);
        }
        #pragma unroll
        for (int kk = 0; kk < 16; ++kk) {
            const float4 aA = *(const float4*)&As[kk][tm4];
            const float4 aB = *(const float4*)&As[kk][tm4 + 64];
            const float4 bA = *(const float4*)&Bs[kk][tn4];
            const float4 bB = *(const float4*)&Bs[kk][tn4 + 32];
            const float av[8] = {aA.x, aA.y, aA.z, aA.w, aB.x, aB.y, aB.z, aB.w};
            const float bv[8] = {bA.x, bA.y, bA.z, bA.w, bB.x, bB.y, bB.z, bB.w};
            #pragma unroll
            for (int i = 0; i < 8; ++i)
                #pragma unroll
                for (int j = 0; j < 8; ++j) acc[i][j] += av[i] * bv[j];
        }
        __syncthreads();
    }

    auto ldbias = [&](int cc) -> float4 {
        if (cc < NOFF) return *(const float4*)&b_off[cc];
        if (cc < NTOT) return *(const float4*)&b_mask[cc - NOFF];
        return float4{0.0f, 0.0f, 0.0f, 0.0f};
    };
    const int c0 = n0 + tn4;
    const int c1 = c0 + 32;
    const float4 bs0 = ldbias(c0);
    const float4 bs1 = ldbias(c1);
    #pragma unroll
    for (int i = 0; i < 8; ++i) {
        const int m = m0 + (i < 4 ? tm4 + i : 64 + tm4 + i - 4);
        float4 o0, o1;
        o0.x = acc[i][0] + bs0.x; o0.y = acc[i][1] + bs0.y;
        o0.z = acc[i][2] + bs0.z; o0.w = acc[i][3] + bs0.w;
        o1.x = acc[i][4] + bs1.x; o1.y = acc[i][5] + bs1.y;
        o1.z = acc[i][6] + bs1.z; o1.w = acc[i][7] + bs1.w;
        if (c0 < NOFF)      *(float4*)&offb[(size_t)m * NOFF + c0] = o0;
        else if (c0 < NTOT) *(float4*)&mskb[(size_t)m * NMSK + (c0 - NOFF)] = o0;
        if (c1 < NOFF)      *(float4*)&offb[(size_t)m * NOFF + c1] = o1;
        else if (c1 < NTOT) *(float4*)&mskb[(size_t)m * NMSK + (c1 - NOFF)] = o1;
    }
}

// ---------------------------------------------------------------------------
// Deformable sampling: block = 4 positions x 64 lanes; precomputed
// mask-folded bilinear weights + corner offsets in LDS; lane owns 4 channels.
// ---------------------------------------------------------------------------
__global__ __launch_bounds__(256)
void sample_kernel(const float* __restrict__ v,
                   const float* __restrict__ offb,
                   const float* __restrict__ mskb,
                   float* __restrict__ s)
{
    __shared__ alignas(16) float loff[POSB][NOFF];
    __shared__ alignas(16) float lmsk[POSB][NMSK];
    __shared__ alignas(16) float wtab[POSB][GRP*NP][4];
    __shared__ alignas(16) int   itab[POSB][GRP*NP][4];

    const int n0 = blockIdx.x * POSB;
    const int t = threadIdx.x;

    // Phase 1: bulk float4 loads of offsets + masks for 4 positions
    if (t < POSB * (NOFF/4)) {                 // 144 threads
        const int q = t / (NOFF/4), r = t % (NOFF/4);
        *(float4*)&loff[q][r*4] = *(const float4*)&offb[(size_t)(n0+q)*NOFF + r*4];
    } else if (t < POSB * (NOFF/4) + POSB * (NMSK/4)) {   // next 72 threads
        const int u = t - POSB * (NOFF/4);
        const int q = u / (NMSK/4), r = u % (NMSK/4);
        *(float4*)&lmsk[q][r*4] = *(const float4*)&mskb[(size_t)(n0+q)*NMSK + r*4];
    }
    __syncthreads();

    // Phase 2: softmax per (pos, group)
    if (t < POSB * GRP) {
        const int q = t >> 3, g = t & 7;
        float* mm = &lmsk[q][g * NP];
        float mx = -1e30f;
        #pragma unroll
        for (int p = 0; p < NP; ++p) mx = fmaxf(mx, mm[p]);
        float sum = 0.0f;
        #pragma unroll
        for (int p = 0; p < NP; ++p) { const float e = __expf(mm[p] - mx); mm[p] = e; sum += e; }
        const float inv = 1.0f / sum;
        #pragma unroll
        for (int p = 0; p < NP; ++p) mm[p] *= inv;
    }
    __syncthreads();

    // Phase 3: per (pos, g, p) weights (mask & validity folded) + offsets
    for (int u = t; u < POSB * GRP * NP; u += 256) {      // 288 slots
        const int q = u / (GRP*NP), j = u % (GRP*NP);
        const int g = j / NP, p = j % NP;
        const int n = n0 + q;
        const int hw = n % HW;
        const int h = hw / WDIM, w = hw % WDIM;
        const float ox = loff[q][g*18 + p*2 + 0];
        const float oy = loff[q][g*18 + p*2 + 1];
        const float m  = lmsk[q][g*NP + p];
        const float px = (float)(w + p/3) + ox;       // padded coords
        const float py = (float)(h + p%3) + oy;
        const float fx = floorf(px), fy = floorf(py);
        const float wx = px - fx, wy = py - fy;
        const int x0 = (int)fx, y0 = (int)fy;
        const int x1 = x0 + 1, y1 = y0 + 1;
        const float vx0 = (x0 >= 1 && x0 < 57) ? 1.0f : 0.0f;
        const float vx1 = (x1 >= 1 && x1 < 57) ? 1.0f : 0.0f;
        const float vy0 = (y0 >= 1 && y0 < 57) ? 1.0f : 0.0f;
        const float vy1 = (y1 >= 1 && y1 < 57) ? 1.0f : 0.0f;
        const int x0c = min(max(x0, 1), 56), x1c = min(max(x1, 1), 56);
        const int y0c = min(max(y0, 1), 56), y1c = min(max(y1, 1), 56);
        wtab[q][j][0] = m * (1.0f-wx) * (1.0f-wy) * vx0 * vy0;
        wtab[q][j][1] = m * wx        * (1.0f-wy) * vx1 * vy0;
        wtab[q][j][2] = m * (1.0f-wx) * wy        * vx0 * vy1;
        wtab[q][j][3] = m * wx        * wy        * vx1 * vy1;
        itab[q][j][0] = ((y0c-1)*WDIM + (x0c-1)) * CH;
        itab[q][j][1] = ((y0c-1)*WDIM + (x1c-1)) * CH;
        itab[q][j][2] = ((y1c-1)*WDIM + (x0c-1)) * CH;
        itab[q][j][3] = ((y1c-1)*WDIM + (x1c-1)) * CH;
    }
    __syncthreads();

    // Phase 4: accumulation. Wave q handles position n0+q; lane owns 4 ch.
    const int q = t >> 6, lane = t & 63;
    const int n = n0 + q;
    const int b = n / HW;
    const int g = lane >> 3;
    const float* vb = v + (size_t)b*HW*CH + lane*4;
    float4 acc = {0.0f, 0.0f, 0.0f, 0.0f};
    #pragma unroll
    for (int p = 0; p < NP; ++p) {
        const int j = g*NP + p;
        const float4 wv = *(const float4*)&wtab[q][j][0];
        const int4  iv = *(const int4*)&itab[q][j][0];
        const float4 c0 = *(const float4*)(vb + iv.x);
        const float4 c1 = *(const float4*)(vb + iv.y);
        const float4 c2 = *(const float4*)(vb + iv.z);
        const float4 c3 = *(const float4*)(vb + iv.w);
        acc.x += wv.x*c0.x + wv.y*c1.x + wv.z*c2.x + wv.w*c3.x;
        acc.y += wv.x*c0.y + wv.y*c1.y + wv.z*c2.y + wv.w*c3.y;
        acc.z += wv.x*c0.z + wv.y*c1.z + wv.z*c2.z + wv.w*c3.z;
        acc.w += wv.x*c0.w + wv.y*c1.w + wv.z*c2.w + wv.w*c3.w;
    }
    *(float4*)&s[(size_t)n*CH + lane*4] = acc;
}

// ---------------------------------------------------------------------------
// GEMM out: y = SiLU(BN(s @ w_out + b_out)), stored NCHW.
// 128x128 tile, 8x8 micro-tile, m-fast map, register-prefetch.
// ---------------------------------------------------------------------------
__global__ __launch_bounds__(256)
void gemm_out_kernel(const float* __restrict__ A,     // s [MTOT,256]
                     const float* __restrict__ Bw,    // w_out [256,256]
                     const float* __restrict__ bias,  // b_out
                     const float* __restrict__ bn_g,
                     const float* __restrict__ bn_b,
                     const float* __restrict__ bn_mean,
                     const float* __restrict__ bn_var,
                     float* __restrict__ y)           // [B,256,3136]
{
    __shared__ alignas(16) float As[16][128];
    __shared__ alignas(16) float Bs[16][128];
    const int m0 = blockIdx.x * 128;
    const int n0 = blockIdx.y * 128;
    const int t = threadIdx.x;
    const int am  = t >> 1;            // A staging row 0..127
    const int ak8 = (t & 1) * 8;       // A staging k base
    const int lk  = t >> 4;            // B staging k
    const int ln4 = (t & 15) * 4;      // B staging n
    const int tm4 = (t & 15) * 4;      // micro rows base (m-fast)
    const int tn4 = (t >> 4) * 4;      // micro cols base
    float acc[8][8] = {};

    const float* arow = A + (size_t)(m0 + am) * CH;
    float4 pa0 = *(const float4*)(arow + ak8);
    float4 pa1 = *(const float4*)(arow + ak8 + 4);
    float4 pb0 = *(const float4*)(Bw + (size_t)lk * CH + n0 + ln4);
    float4 pb1 = *(const float4*)(Bw + (size_t)lk * CH + n0 + ln4 + 64);

    for (int k0 = 0; k0 < CH; k0 += 16) {
        As[ak8 + 0][am] = pa0.x; As[ak8 + 1][am] = pa0.y;
        As[ak8 + 2][am] = pa0.z; As[ak8 + 3][am] = pa0.w;
        As[ak8 + 4][am] = pa1.x; As[ak8 + 5][am] = pa1.y;
        As[ak8 + 6][am] = pa1.z; As[ak8 + 7][am] = pa1.w;
        *(float4*)&Bs[lk][ln4]      = pb0;
        *(float4*)&Bs[lk][ln4 + 64] = pb1;
        __syncthreads();
        if (k0 + 16 < CH) {
            pa0 = *(const float4*)(arow + k0 + 16 + ak8);
            pa1 = *(const float4*)(arow + k0 + 16 + ak8 + 4);
            pb0 = *(const float4*)(Bw + (size_t)(k0 + 16 + lk) * CH + n0 + ln4);
            pb1 = *(const float4*)(Bw + (size_t)(k0 + 16 + lk) * CH + n0 + ln4 + 64);
        }
        #pragma unroll
        for (int kk = 0; kk < 16; ++kk) {
            const float4 aA = *(const float4*)&As[kk][tm4];
            const float4 aB = *(const float4*)&As[kk][tm4 + 64];
            const float4 bA = *(const float4*)&Bs[kk][tn4];
            const float4 bB = *(const float4*)&Bs[kk][tn4 + 64];
            const float av[8] = {aA.x, aA.y, aA.z, aA.w, aB.x, aB.y, aB.z, aB.w};
            const float bv[8] = {bA.x, bA.y, bA.z, bA.w, bB.x, bB.y, bB.z, bB.w};
            #pragma unroll
            for (int i = 0; i < 8; ++i)
                #pragma unroll
                for (int j = 0; j < 8; ++j) acc[i][j] += av[i] * bv[j];
        }
        __syncthreads();
    }
    // rows: m0+tm4+0..3 (i=0..3), m0+64+tm4+0..3 (i=4..7); HW%4==0 -> no straddle
    const int mr0 = m0 + tm4;
    const int mr1 = m0 + 64 + tm4;
    const size_t yo0 = (size_t)(mr0 / HW) * CH * HW + (mr0 % HW);
    const size_t yo1 = (size_t)(mr1 / HW) * CH * HW + (mr1 % HW);
    #pragma unroll
    for (int j = 0; j < 8; ++j) {
        const int nn = n0 + (j < 4 ? tn4 + j : 64 + tn4 + j - 4);
        const float sc = bn_g[nn] * rsqrtf(bn_var[nn] + 1e-5f);
        const float sh = bn_b[nn] - bn_mean[nn] * sc;
        const float bs = bias[nn];
        float4 o0, o1;
        #pragma unroll
        for (int i = 0; i < 4; ++i) {
            float val = (acc[i][j] + bs) * sc + sh;
            ((float*)&o0)[i] = val / (1.0f + expf(-val));   // SiLU
            float val2 = (acc[i + 4][j] + bs) * sc + sh;
            ((float*)&o1)[i] = val2 / (1.0f + expf(-val2));
        }
        *(float4*)&y[yo0 + (size_t)nn * HW] = o0;
        *(float4*)&y[yo1 + (size_t)nn * HW] = o1;
    }
}

extern "C" void kernel_launch(void* const* d_in, const int* in_sizes, int n_in,
                              void* d_out, int out_size, void* d_ws, size_t ws_size,
                              hipStream_t stream) {
    const float* x      = (const float*)d_in[0];
    const float* w_in   = (const float*)d_in[1];
    const float* b_in   = (const float*)d_in[2];
    const float* dw_w   = (const float*)d_in[3];
    const float* dw_b   = (const float*)d_in[4];
    const float* ln_g   = (const float*)d_in[5];
    const float* ln_b   = (const float*)d_in[6];
    const float* w_off  = (const float*)d_in[7];
    const float* b_off  = (const float*)d_in[8];
    const float* w_mask = (const float*)d_in[9];
    const float* b_mask = (const float*)d_in[10];
    const float* w_out  = (const float*)d_in[11];
    const float* b_out  = (const float*)d_in[12];
    const float* bn_g   = (const float*)d_in[13];
    const float* bn_b   = (const float*)d_in[14];
    const float* bn_mean= (const float*)d_in[15];
    const float* bn_var = (const float*)d_in[16];
    float* out = (float*)d_out;

    float* ws   = (float*)d_ws;
    float* v    = ws;                                   // MTOT*CH
    float* f    = v + (size_t)MTOT*CH;                  // MTOT*CH
    float* offb = f + (size_t)MTOT*CH;                  // MTOT*NOFF
    float* mskb = offb + (size_t)MTOT*NOFF;             // MTOT*NMSK
    float* s    = f;                                    // reuse f buffer

    gemm_in_kernel<<<dim3(MTOT/128, CH/128), dim3(256), 0, stream>>>(x, w_in, b_in, v);
    dw_ln_gelu_kernel<<<dim3(HDIM, BATCH), dim3(256), 0, stream>>>(x, dw_w, dw_b, ln_g, ln_b, f);
    gemm_offmask_kernel<<<dim3((NTOT + 63)/64, MTOT/128), dim3(128), 0, stream>>>(
        f, w_off, b_off, w_mask, b_mask, offb, mskb);
    sample_kernel<<<dim3(MTOT/POSB), dim3(256), 0, stream>>>(v, offb, mskb, s);
    gemm_out_kernel<<<dim3(MTOT/128, CH/128), dim3(256), 0, stream>>>(s, w_out, b_out, bn_g, bn_b, bn_mean, bn_var, out);
}

// Round 8
// 341.209 us; speedup vs baseline: 1.1103x; 1.0294x over previous
//
#include <hip/hip_runtime.h>
#include <math.h>

// Problem constants
#define BATCH 8
#define CH    256
#define HDIM  56
#define WDIM  56
#define HW    (HDIM*WDIM)          // 3136
#define MTOT  (BATCH*HW)           // 25088
#define GRP   8
#define GC    32
#define NP    9                    // K*K
#define NOFF  (GRP*NP*2)           // 144
#define NMSK  (GRP*NP)             // 72
#define NTOT  (NOFF+NMSK)          // 216
#define POSB  4                    // positions per sample block

typedef float f32x4 __attribute__((ext_vector_type(4)));
typedef short s16x8 __attribute__((ext_vector_type(8)));

// split a,b into packed bf16 hi (truncation) and bf16 lo (exact remainder, truncated)
__device__ inline void split2(float a, float b, unsigned int& hp, unsigned int& lp)
{
    const unsigned int ua = __float_as_uint(a), ub = __float_as_uint(b);
    hp = (ub & 0xffff0000u) | (ua >> 16);
    const float ha = __uint_as_float(ua & 0xffff0000u);
    const float hb = __uint_as_float(ub & 0xffff0000u);
    const unsigned int la = __float_as_uint(a - ha), lb = __float_as_uint(b - hb);
    lp = (lb & 0xffff0000u) | (la >> 16);
}

// ---------------------------------------------------------------------------
// GEMM 1: v[m][n] = sum_k x[b][k][hw] * w_in[k][n] + b_in[n]  (fp32, unchanged)
// ---------------------------------------------------------------------------
__global__ __launch_bounds__(256)
void gemm_in_kernel(const float* __restrict__ x,
                    const float* __restrict__ w_in,
                    const float* __restrict__ b_in,
                    float* __restrict__ v)
{
    __shared__ alignas(16) float As[16][128];
    __shared__ alignas(16) float Bs[16][128];
    const int m0 = blockIdx.x * 128;
    const int n0 = blockIdx.y * 128;
    const int t = threadIdx.x;
    const int lk  = t >> 4;
    const int lm4 = (t & 15) * 4;
    const int tm4 = (t >> 4) * 4;
    const int tn4 = (t & 15) * 4;
    float acc[8][8] = {};

    const int mA0 = m0 + lm4, mA1 = m0 + lm4 + 64;
    const size_t aoff0 = (size_t)(mA0 / HW) * CH * HW + (mA0 % HW);
    const size_t aoff1 = (size_t)(mA1 / HW) * CH * HW + (mA1 % HW);

    float4 pa0 = *(const float4*)(x + aoff0 + (size_t)lk * HW);
    float4 pa1 = *(const float4*)(x + aoff1 + (size_t)lk * HW);
    float4 pb0 = *(const float4*)(w_in + (size_t)lk * CH + n0 + lm4);
    float4 pb1 = *(const float4*)(w_in + (size_t)lk * CH + n0 + lm4 + 64);

    for (int k0 = 0; k0 < CH; k0 += 16) {
        *(float4*)&As[lk][lm4]      = pa0;
        *(float4*)&As[lk][lm4 + 64] = pa1;
        *(float4*)&Bs[lk][lm4]      = pb0;
        *(float4*)&Bs[lk][lm4 + 64] = pb1;
        __syncthreads();
        if (k0 + 16 < CH) {
            const int k = k0 + 16 + lk;
            pa0 = *(const float4*)(x + aoff0 + (size_t)k * HW);
            pa1 = *(const float4*)(x + aoff1 + (size_t)k * HW);
            pb0 = *(const float4*)(w_in + (size_t)k * CH + n0 + lm4);
            pb1 = *(const float4*)(w_in + (size_t)k * CH + n0 + lm4 + 64);
        }
        #pragma unroll
        for (int kk = 0; kk < 16; ++kk) {
            const float4 aA = *(const float4*)&As[kk][tm4];
            const float4 aB = *(const float4*)&As[kk][tm4 + 64];
            const float4 bA = *(const float4*)&Bs[kk][tn4];
            const float4 bB = *(const float4*)&Bs[kk][tn4 + 64];
            const float av[8] = {aA.x, aA.y, aA.z, aA.w, aB.x, aB.y, aB.z, aB.w};
            const float bv[8] = {bA.x, bA.y, bA.z, bA.w, bB.x, bB.y, bB.z, bB.w};
            #pragma unroll
            for (int i = 0; i < 8; ++i)
                #pragma unroll
                for (int j = 0; j < 8; ++j) acc[i][j] += av[i] * bv[j];
        }
        __syncthreads();
    }
    const float4 biasA = *(const float4*)&b_in[n0 + tn4];
    const float4 biasB = *(const float4*)&b_in[n0 + tn4 + 64];
    #pragma unroll
    for (int i = 0; i < 8; ++i) {
        const int m = m0 + (i < 4 ? tm4 + i : 64 + tm4 + i - 4);
        float4 o0, o1;
        o0.x = acc[i][0] + biasA.x; o0.y = acc[i][1] + biasA.y;
        o0.z = acc[i][2] + biasA.z; o0.w = acc[i][3] + biasA.w;
        o1.x = acc[i][4] + biasB.x; o1.y = acc[i][5] + biasB.y;
        o1.z = acc[i][6] + biasB.z; o1.w = acc[i][7] + biasB.w;
        *(float4*)&v[(size_t)m * CH + n0 + tn4]      = o0;
        *(float4*)&v[(size_t)m * CH + n0 + tn4 + 64] = o1;
    }
}

// ---------------------------------------------------------------------------
// Fused depthwise 3x3 + bias + LayerNorm(C) + exact GELU -> f (NHWC) (unchanged)
// ---------------------------------------------------------------------------
__global__ __launch_bounds__(256)
void dw_ln_gelu_kernel(const float* __restrict__ x,
                       const float* __restrict__ dw_w,
                       const float* __restrict__ dw_b,
                       const float* __restrict__ ln_g,
                       const float* __restrict__ ln_b,
                       float* __restrict__ f)
{
    __shared__ float tile[WDIM][CH + 1];
    __shared__ float red1[WDIM][4], red2[WDIM][4];
    __shared__ float meanA[WDIM], rstdA[WDIM];

    const int h = blockIdx.x;
    const int b = blockIdx.y;
    const int t = threadIdx.x;
    const int lane = t & 63;
    const int wv   = t >> 6;

    for (int cg = 0; cg < CH / 4; ++cg) {
        const int c = cg * 4 + wv;
        const float* xp = x + ((size_t)b * CH + c) * HW;
        float rowv[3];
        #pragma unroll
        for (int r = 0; r < 3; ++r) {
            const int hh = h + r - 1;
            rowv[r] = (lane < WDIM && hh >= 0 && hh < HDIM) ? xp[hh * WDIM + lane] : 0.0f;
        }
        const float* wp = dw_w + c * 9;
        float acc = dw_b[c];
        #pragma unroll
        for (int r = 0; r < 3; ++r) {
            float L = __shfl_up(rowv[r], 1);
            float R = __shfl_down(rowv[r], 1);
            if (lane == 0) L = 0.0f;
            acc += L * wp[r * 3 + 0] + rowv[r] * wp[r * 3 + 1] + R * wp[r * 3 + 2];
        }
        if (lane < WDIM)
            tile[lane][c] = acc;
    }
    __syncthreads();

    if (t < 224) {
        const int p = t >> 2, q = t & 3;
        float s1 = 0.0f, s2 = 0.0f;
        #pragma unroll 8
        for (int i = 0; i < 64; ++i) {
            const float v = tile[p][q * 64 + i];
            s1 += v; s2 += v * v;
        }
        red1[p][q] = s1; red2[p][q] = s2;
    }
    __syncthreads();
    if (t < WDIM) {
        const float s1 = red1[t][0] + red1[t][1] + red1[t][2] + red1[t][3];
        const float s2 = red2[t][0] + red2[t][1] + red2[t][2] + red2[t][3];
        const float m = s1 * (1.0f / 256.0f);
        const float var = s2 * (1.0f / 256.0f) - m * m;
        meanA[t] = m;
        rstdA[t] = rsqrtf(var + 1e-5f);
    }
    __syncthreads();

    const float gam = ln_g[t], bet = ln_b[t];
    const size_t n0 = (size_t)(b * HDIM + h) * WDIM;
    for (int p = 0; p < WDIM; ++p) {
        const float xn = (tile[p][t] - meanA[p]) * rstdA[p] * gam + bet;
        const float g = 0.5f * xn * (1.0f + erff(xn * 0.70710678118654752f));
        f[(n0 + p) * CH + t] = g;
    }
}

// ---------------------------------------------------------------------------
// Fused offset+mask GEMM. Fixed A staging: cooperative 64B-segment loads into
// transposed As[k][m] (pitch 132 -> 2-way bank aliasing only).
// ---------------------------------------------------------------------------
__global__ __launch_bounds__(128)
void gemm_offmask_kernel(const float* __restrict__ A,      // f [MTOT,256]
                         const float* __restrict__ w_off,  // [256,144]
                         const float* __restrict__ b_off,
                         const float* __restrict__ w_mask, // [256,72]
                         const float* __restrict__ b_mask,
                         float* __restrict__ offb,         // [MTOT,144]
                         float* __restrict__ mskb)         // [MTOT,72]
{
    __shared__ alignas(16) float As[16][132];  // [k][m], padded
    __shared__ alignas(16) float Bs[16][64];
    const int m0 = blockIdx.x * 128;
    const int n0 = blockIdx.y * 64;
    const int t = threadIdx.x;          // 0..127
    const int ar  = t >> 2;             // A staging row base (32 rows/pass)
    const int ac  = (t & 3) * 4;        // A staging k-col
    const int bkk = t & 15;             // B staging k row
    const int bc  = n0 + (t >> 4) * 8;  // B staging col base
    const int tm4 = (t & 15) * 4;       // micro rows base (split {0,64})
    const int tn4 = (t >> 4) * 4;       // micro cols base (split {0,32})
    float acc[8][8] = {};

    auto ldb = [&](int k, int cc) -> float4 {
        if (cc < NOFF) return *(const float4*)&w_off[(size_t)k * NOFF + cc];
        if (cc < NTOT) return *(const float4*)&w_mask[(size_t)k * NMSK + (cc - NOFF)];
        return float4{0.0f, 0.0f, 0.0f, 0.0f};
    };

    float4 pa[4];
    #pragma unroll
    for (int p = 0; p < 4; ++p)
        pa[p] = *(const float4*)(A + (size_t)(m0 + ar + p*32) * CH + ac);
    float4 pb0 = ldb(bkk, bc);
    float4 pb1 = ldb(bkk, bc + 4);

    for (int k0 = 0; k0 < CH; k0 += 16) {
        #pragma unroll
        for (int p = 0; p < 4; ++p) {
            As[ac + 0][ar + p*32] = pa[p].x;
            As[ac + 1][ar + p*32] = pa[p].y;
            As[ac + 2][ar + p*32] = pa[p].z;
            As[ac + 3][ar + p*32] = pa[p].w;
        }
        *(float4*)&Bs[bkk][(t >> 4) * 8]     = pb0;
        *(float4*)&Bs[bkk][(t >> 4) * 8 + 4] = pb1;
        __syncthreads();
        if (k0 + 16 < CH) {
            #pragma unroll
            for (int p = 0; p < 4; ++p)
                pa[p] = *(const float4*)(A + (size_t)(m0 + ar + p*32) * CH + k0 + 16 + ac);
            pb0 = ldb(k0 + 16 + bkk, bc);
            pb1 = ldb(k0 + 16 + bkk, bc + 4);
        }
        #pragma unroll
        for (int kk = 0; kk < 16; ++kk) {
            const float4 aA = *(const float4*)&As[kk][tm4];
            const float4 aB = *(const float4*)&As[kk][tm4 + 64];
            const float4 bA = *(const float4*)&Bs[kk][tn4];
            const float4 bB = *(const float4*)&Bs[kk][tn4 + 32];
            const float av[8] = {aA.x, aA.y, aA.z, aA.w, aB.x, aB.y, aB.z, aB.w};
            const float bv[8] = {bA.x, bA.y, bA.z, bA.w, bB.x, bB.y, bB.z, bB.w};
            #pragma unroll
            for (int i = 0; i < 8; ++i)
                #pragma unroll
                for (int j = 0; j < 8; ++j) acc[i][j] += av[i] * bv[j];
        }
        __syncthreads();
    }

    auto ldbias = [&](int cc) -> float4 {
        if (cc < NOFF) return *(const float4*)&b_off[cc];
        if (cc < NTOT) return *(const float4*)&b_mask[cc - NOFF];
        return float4{0.0f, 0.0f, 0.0f, 0.0f};
    };
    const int c0 = n0 + tn4;
    const int c1 = c0 + 32;
    const float4 bs0 = ldbias(c0);
    const float4 bs1 = ldbias(c1);
    #pragma unroll
    for (int i = 0; i < 8; ++i) {
        const int m = m0 + (i < 4 ? tm4 + i : 64 + tm4 + i - 4);
        float4 o0, o1;
        o0.x = acc[i][0] + bs0.x; o0.y = acc[i][1] + bs0.y;
        o0.z = acc[i][2] + bs0.z; o0.w = acc[i][3] + bs0.w;
        o1.x = acc[i][4] + bs1.x; o1.y = acc[i][5] + bs1.y;
        o1.z = acc[i][6] + bs1.z; o1.w = acc[i][7] + bs1.w;
        if (c0 < NOFF)      *(float4*)&offb[(size_t)m * NOFF + c0] = o0;
        else if (c0 < NTOT) *(float4*)&mskb[(size_t)m * NMSK + (c0 - NOFF)] = o0;
        if (c1 < NOFF)      *(float4*)&offb[(size_t)m * NOFF + c1] = o1;
        else if (c1 < NTOT) *(float4*)&mskb[(size_t)m * NMSK + (c1 - NOFF)] = o1;
    }
}

// ---------------------------------------------------------------------------
// Deformable sampling (unchanged).
// ---------------------------------------------------------------------------
__global__ __launch_bounds__(256)
void sample_kernel(const float* __restrict__ v,
                   const float* __restrict__ offb,
                   const float* __restrict__ mskb,
                   float* __restrict__ s)
{
    __shared__ alignas(16) float loff[POSB][NOFF];
    __shared__ alignas(16) float lmsk[POSB][NMSK];
    __shared__ alignas(16) float wtab[POSB][GRP*NP][4];
    __shared__ alignas(16) int   itab[POSB][GRP*NP][4];

    const int n0 = blockIdx.x * POSB;
    const int t = threadIdx.x;

    if (t < POSB * (NOFF/4)) {
        const int q = t / (NOFF/4), r = t % (NOFF/4);
        *(float4*)&loff[q][r*4] = *(const float4*)&offb[(size_t)(n0+q)*NOFF + r*4];
    } else if (t < POSB * (NOFF/4) + POSB * (NMSK/4)) {
        const int u = t - POSB * (NOFF/4);
        const int q = u / (NMSK/4), r = u % (NMSK/4);
        *(float4*)&lmsk[q][r*4] = *(const float4*)&mskb[(size_t)(n0+q)*NMSK + r*4];
    }
    __syncthreads();

    if (t < POSB * GRP) {
        const int q = t >> 3, g = t & 7;
        float* mm = &lmsk[q][g * NP];
        float mx = -1e30f;
        #pragma unroll
        for (int p = 0; p < NP; ++p) mx = fmaxf(mx, mm[p]);
        float sum = 0.0f;
        #pragma unroll
        for (int p = 0; p < NP; ++p) { const float e = __expf(mm[p] - mx); mm[p] = e; sum += e; }
        const float inv = 1.0f / sum;
        #pragma unroll
        for (int p = 0; p < NP; ++p) mm[p] *= inv;
    }
    __syncthreads();

    for (int u = t; u < POSB * GRP * NP; u += 256) {
        const int q = u / (GRP*NP), j = u % (GRP*NP);
        const int g = j / NP, p = j % NP;
        const int n = n0 + q;
        const int hw = n % HW;
        const int h = hw / WDIM, w = hw % WDIM;
        const float ox = loff[q][g*18 + p*2 + 0];
        const float oy = loff[q][g*18 + p*2 + 1];
        const float m  = lmsk[q][g*NP + p];
        const float px = (float)(w + p/3) + ox;
        const float py = (float)(h + p%3) + oy;
        const float fx = floorf(px), fy = floorf(py);
        const float wx = px - fx, wy = py - fy;
        const int x0 = (int)fx, y0 = (int)fy;
        const int x1 = x0 + 1, y1 = y0 + 1;
        const float vx0 = (x0 >= 1 && x0 < 57) ? 1.0f : 0.0f;
        const float vx1 = (x1 >= 1 && x1 < 57) ? 1.0f : 0.0f;
        const float vy0 = (y0 >= 1 && y0 < 57) ? 1.0f : 0.0f;
        const float vy1 = (y1 >= 1 && y1 < 57) ? 1.0f : 0.0f;
        const int x0c = min(max(x0, 1), 56), x1c = min(max(x1, 1), 56);
        const int y0c = min(max(y0, 1), 56), y1c = min(max(y1, 1), 56);
        wtab[q][j][0] = m * (1.0f-wx) * (1.0f-wy) * vx0 * vy0;
        wtab[q][j][1] = m * wx        * (1.0f-wy) * vx1 * vy0;
        wtab[q][j][2] = m * (1.0f-wx) * wy        * vx0 * vy1;
        wtab[q][j][3] = m * wx        * wy        * vx1 * vy1;
        itab[q][j][0] = ((y0c-1)*WDIM + (x0c-1)) * CH;
        itab[q][j][1] = ((y0c-1)*WDIM + (x1c-1)) * CH;
        itab[q][j][2] = ((y1c-1)*WDIM + (x0c-1)) * CH;
        itab[q][j][3] = ((y1c-1)*WDIM + (x1c-1)) * CH;
    }
    __syncthreads();

    const int q = t >> 6, lane = t & 63;
    const int n = n0 + q;
    const int b = n / HW;
    const int g = lane >> 3;
    const float* vb = v + (size_t)b*HW*CH + lane*4;
    float4 acc = {0.0f, 0.0f, 0.0f, 0.0f};
    #pragma unroll
    for (int p = 0; p < NP; ++p) {
        const int j = g*NP + p;
        const float4 wv = *(const float4*)&wtab[q][j][0];
        const int4  iv = *(const int4*)&itab[q][j][0];
        const float4 c0 = *(const float4*)(vb + iv.x);
        const float4 c1 = *(const float4*)(vb + iv.y);
        const float4 c2 = *(const float4*)(vb + iv.z);
        const float4 c3 = *(const float4*)(vb + iv.w);
        acc.x += wv.x*c0.x + wv.y*c1.x + wv.z*c2.x + wv.w*c3.x;
        acc.y += wv.x*c0.y + wv.y*c1.y + wv.z*c2.y + wv.w*c3.y;
        acc.z += wv.x*c0.z + wv.y*c1.z + wv.z*c2.z + wv.w*c3.z;
        acc.w += wv.x*c0.w + wv.y*c1.w + wv.z*c2.w + wv.w*c3.w;
    }
    *(float4*)&s[(size_t)n*CH + lane*4] = acc;
}

// ---------------------------------------------------------------------------
// Transpose + hi/lo bf16 split of w_out: [k][n] fp32 -> wt_hi/wt_lo [n][k] bf16.
// ---------------------------------------------------------------------------
__global__ __launch_bounds__(256)
void wt_split_kernel(const float* __restrict__ w,
                     unsigned short* __restrict__ hi,
                     unsigned short* __restrict__ lo)
{
    __shared__ float lds[64][68];
    const int kt = blockIdx.x * 64, nt = blockIdx.y * 64;
    const int t = threadIdx.x;
    #pragma unroll
    for (int p = 0; p < 4; ++p) {
        const int kr = (t >> 4) + p * 16, nc = (t & 15) * 4;
        *(float4*)&lds[kr][nc] = *(const float4*)(w + (size_t)(kt + kr) * CH + nt + nc);
    }
    __syncthreads();
    const int nl = t >> 2, kc = (t & 3) * 16;
    #pragma unroll
    for (int j = 0; j < 16; j += 2) {
        const float f0 = lds[kc + j][nl], f1 = lds[kc + j + 1][nl];
        unsigned int hp, lp;
        split2(f0, f1, hp, lp);
        *(unsigned int*)&hi[(size_t)(nt + nl) * CH + kt + kc + j] = hp;
        *(unsigned int*)&lo[(size_t)(nt + nl) * CH + kt + kc + j] = lp;
    }
}

// ---------------------------------------------------------------------------
// GEMM out via bf16 MFMA (split hi/lo, 3 products): y = SiLU(BN(s@w_out+b)).
// Block 256 thr = 4 waves, tile 256m x 64n (wave = 64m x 64n). NO LDS, NO
// barriers: w-frags load directly from pre-transposed wt_[hi|lo][n][k] bf16
// (L2-resident); s-frags load fp32 rows (k-contiguous) and split in-register.
// A-operand = weights (D row = n), B-operand = s (D col = m = lane&15) so
// NCHW stores are 64B-contiguous hw runs.
// ---------------------------------------------------------------------------
__global__ __launch_bounds__(256)
void gemm_out_mfma(const float* __restrict__ A,            // s [MTOT,256]
                   const unsigned short* __restrict__ whi, // [256 n][256 k] bf16
                   const unsigned short* __restrict__ wlo,
                   const float* __restrict__ bias,
                   const float* __restrict__ bn_g,
                   const float* __restrict__ bn_b,
                   const float* __restrict__ bn_mean,
                   const float* __restrict__ bn_var,
                   float* __restrict__ y)                  // [B,256,3136]
{
    const int m0 = blockIdx.x * 256;
    const int n0 = blockIdx.y * 64;
    const int t = threadIdx.x;
    const int lane = t & 63, wv = t >> 6;
    const int mblk = m0 + wv * 64;
    const int fm = lane & 15;     // fragment free index
    const int q  = lane >> 4;     // quad

    f32x4 acc[4][4];              // [nt][mt]
    const f32x4 zero = {0.0f, 0.0f, 0.0f, 0.0f};
    #pragma unroll
    for (int i = 0; i < 4; ++i)
        #pragma unroll
        for (int j = 0; j < 4; ++j) acc[i][j] = zero;

    const float* arow[4];
    const unsigned short* wrh[4];
    const unsigned short* wrl[4];
    #pragma unroll
    for (int mt = 0; mt < 4; ++mt)
        arow[mt] = A + (size_t)(mblk + mt*16 + fm) * CH + q * 8;
    #pragma unroll
    for (int nt = 0; nt < 4; ++nt) {
        wrh[nt] = whi + (size_t)(n0 + nt*16 + fm) * CH + q * 8;
        wrl[nt] = wlo + (size_t)(n0 + nt*16 + fm) * CH + q * 8;
    }

    for (int k0 = 0; k0 < CH; k0 += 32) {
        s16x8 wh[4], wl[4], sh[4], sl[4];
        #pragma unroll
        for (int nt = 0; nt < 4; ++nt) {
            wh[nt] = *(const s16x8*)(wrh[nt] + k0);
            wl[nt] = *(const s16x8*)(wrl[nt] + k0);
        }
        #pragma unroll
        for (int mt = 0; mt < 4; ++mt) {
            const f32x4 r0 = *(const f32x4*)(arow[mt] + k0);
            const f32x4 r1 = *(const f32x4*)(arow[mt] + k0 + 4);
            union { s16x8 v; unsigned int u[4]; } ph, pl;
            split2(r0[0], r0[1], ph.u[0], pl.u[0]);
            split2(r0[2], r0[3], ph.u[1], pl.u[1]);
            split2(r1[0], r1[1], ph.u[2], pl.u[2]);
            split2(r1[2], r1[3], ph.u[3], pl.u[3]);
            sh[mt] = ph.v; sl[mt] = pl.v;
        }
        #pragma unroll
        for (int nt = 0; nt < 4; ++nt)
            #pragma unroll
            for (int mt = 0; mt < 4; ++mt) {
                acc[nt][mt] = __builtin_amdgcn_mfma_f32_16x16x32_bf16(wh[nt], sh[mt], acc[nt][mt], 0, 0, 0);
                acc[nt][mt] = __builtin_amdgcn_mfma_f32_16x16x32_bf16(wh[nt], sl[mt], acc[nt][mt], 0, 0, 0);
                acc[nt][mt] = __builtin_amdgcn_mfma_f32_16x16x32_bf16(wl[nt], sh[mt], acc[nt][mt], 0, 0, 0);
            }
    }

    // epilogue: lane holds D[n = q*4+r][m = fm] per (nt, mt) tile
    #pragma unroll
    for (int nt = 0; nt < 4; ++nt) {
        #pragma unroll
        for (int r = 0; r < 4; ++r) {
            const int n = n0 + nt*16 + q*4 + r;
            const float sc = bn_g[n] * rsqrtf(bn_var[n] + 1e-5f);
            const float sb = bn_b[n] - bn_mean[n] * sc;
            const float bs = bias[n];
            #pragma unroll
            for (int mt = 0; mt < 4; ++mt) {
                const int mm = mblk + mt*16;
                const size_t base = (size_t)(mm / HW) * CH * HW + (mm % HW);
                float val = (acc[nt][mt][r] + bs) * sc + sb;
                y[base + (size_t)n * HW + fm] = val / (1.0f + expf(-val));
            }
        }
    }
}

extern "C" void kernel_launch(void* const* d_in, const int* in_sizes, int n_in,
                              void* d_out, int out_size, void* d_ws, size_t ws_size,
                              hipStream_t stream) {
    const float* x      = (const float*)d_in[0];
    const float* w_in   = (const float*)d_in[1];
    const float* b_in   = (const float*)d_in[2];
    const float* dw_w   = (const float*)d_in[3];
    const float* dw_b   = (const float*)d_in[4];
    const float* ln_g   = (const float*)d_in[5];
    const float* ln_b   = (const float*)d_in[6];
    const float* w_off  = (const float*)d_in[7];
    const float* b_off  = (const float*)d_in[8];
    const float* w_mask = (const float*)d_in[9];
    const float* b_mask = (const float*)d_in[10];
    const float* w_out  = (const float*)d_in[11];
    const float* b_out  = (const float*)d_in[12];
    const float* bn_g   = (const float*)d_in[13];
    const float* bn_b   = (const float*)d_in[14];
    const float* bn_mean= (const float*)d_in[15];
    const float* bn_var = (const float*)d_in[16];
    float* out = (float*)d_out;

    float* ws   = (float*)d_ws;
    float* v    = ws;                                   // MTOT*CH
    float* f    = v + (size_t)MTOT*CH;                  // MTOT*CH
    float* offb = f + (size_t)MTOT*CH;                  // MTOT*NOFF
    float* mskb = offb + (size_t)MTOT*NOFF;             // MTOT*NMSK
    float* s    = f;                                    // reuse f buffer
    unsigned short* wt_hi = (unsigned short*)(mskb + (size_t)MTOT*NMSK);  // 256*256 bf16
    unsigned short* wt_lo = wt_hi + CH*CH;

    wt_split_kernel<<<dim3(4, 4), dim3(256), 0, stream>>>(w_out, wt_hi, wt_lo);
    gemm_in_kernel<<<dim3(MTOT/128, CH/128), dim3(256), 0, stream>>>(x, w_in, b_in, v);
    dw_ln_gelu_kernel<<<dim3(HDIM, BATCH), dim3(256), 0, stream>>>(x, dw_w, dw_b, ln_g, ln_b, f);
    gemm_offmask_kernel<<<dim3(MTOT/128, (NTOT + 63)/64), dim3(128), 0, stream>>>(
        f, w_off, b_off, w_mask, b_mask, offb, mskb);
    sample_kernel<<<dim3(MTOT/POSB), dim3(256), 0, stream>>>(v, offb, mskb, s);
    gemm_out_mfma<<<dim3(MTOT/256, CH/64), dim3(256), 0, stream>>>(
        s, wt_hi, wt_lo, b_out, bn_g, bn_b, bn_mean, bn_var, out);
}

// Round 9
// 340.204 us; speedup vs baseline: 1.1135x; 1.0030x over previous
//
#include <hip/hip_runtime.h>
#include <math.h>

// Problem constants
#define BATCH 8
#define CH    256
#define HDIM  56
#define WDIM  56
#define HW    (HDIM*WDIM)          // 3136
#define MTOT  (BATCH*HW)           // 25088
#define GRP   8
#define GC    32
#define NP    9                    // K*K
#define NOFF  (GRP*NP*2)           // 144
#define NMSK  (GRP*NP)             // 72
#define NTOT  (NOFF+NMSK)          // 216
#define POSB  4                    // positions per sample block

typedef float f32x4 __attribute__((ext_vector_type(4)));
typedef short s16x8 __attribute__((ext_vector_type(8)));

// split a,b into packed bf16 hi (truncation) and bf16 lo (exact remainder, truncated)
__device__ inline void split2(float a, float b, unsigned int& hp, unsigned int& lp)
{
    const unsigned int ua = __float_as_uint(a), ub = __float_as_uint(b);
    hp = (ub & 0xffff0000u) | (ua >> 16);
    const float ha = __uint_as_float(ua & 0xffff0000u);
    const float hb = __uint_as_float(ub & 0xffff0000u);
    const unsigned int la = __float_as_uint(a - ha), lb = __float_as_uint(b - hb);
    lp = (lb & 0xffff0000u) | (la >> 16);
}

// ---------------------------------------------------------------------------
// GEMM 1: v[m][n] = sum_k x[b][k][hw] * w_in[k][n] + b_in[n]  (fp32)
// ---------------------------------------------------------------------------
__global__ __launch_bounds__(256)
void gemm_in_kernel(const float* __restrict__ x,
                    const float* __restrict__ w_in,
                    const float* __restrict__ b_in,
                    float* __restrict__ v)
{
    __shared__ alignas(16) float As[16][128];
    __shared__ alignas(16) float Bs[16][128];
    const int m0 = blockIdx.x * 128;
    const int n0 = blockIdx.y * 128;
    const int t = threadIdx.x;
    const int lk  = t >> 4;
    const int lm4 = (t & 15) * 4;
    const int tm4 = (t >> 4) * 4;
    const int tn4 = (t & 15) * 4;
    float acc[8][8] = {};

    const int mA0 = m0 + lm4, mA1 = m0 + lm4 + 64;
    const size_t aoff0 = (size_t)(mA0 / HW) * CH * HW + (mA0 % HW);
    const size_t aoff1 = (size_t)(mA1 / HW) * CH * HW + (mA1 % HW);

    float4 pa0 = *(const float4*)(x + aoff0 + (size_t)lk * HW);
    float4 pa1 = *(const float4*)(x + aoff1 + (size_t)lk * HW);
    float4 pb0 = *(const float4*)(w_in + (size_t)lk * CH + n0 + lm4);
    float4 pb1 = *(const float4*)(w_in + (size_t)lk * CH + n0 + lm4 + 64);

    for (int k0 = 0; k0 < CH; k0 += 16) {
        *(float4*)&As[lk][lm4]      = pa0;
        *(float4*)&As[lk][lm4 + 64] = pa1;
        *(float4*)&Bs[lk][lm4]      = pb0;
        *(float4*)&Bs[lk][lm4 + 64] = pb1;
        __syncthreads();
        if (k0 + 16 < CH) {
            const int k = k0 + 16 + lk;
            pa0 = *(const float4*)(x + aoff0 + (size_t)k * HW);
            pa1 = *(const float4*)(x + aoff1 + (size_t)k * HW);
            pb0 = *(const float4*)(w_in + (size_t)k * CH + n0 + lm4);
            pb1 = *(const float4*)(w_in + (size_t)k * CH + n0 + lm4 + 64);
        }
        #pragma unroll
        for (int kk = 0; kk < 16; ++kk) {
            const float4 aA = *(const float4*)&As[kk][tm4];
            const float4 aB = *(const float4*)&As[kk][tm4 + 64];
            const float4 bA = *(const float4*)&Bs[kk][tn4];
            const float4 bB = *(const float4*)&Bs[kk][tn4 + 64];
            const float av[8] = {aA.x, aA.y, aA.z, aA.w, aB.x, aB.y, aB.z, aB.w};
            const float bv[8] = {bA.x, bA.y, bA.z, bA.w, bB.x, bB.y, bB.z, bB.w};
            #pragma unroll
            for (int i = 0; i < 8; ++i)
                #pragma unroll
                for (int j = 0; j < 8; ++j) acc[i][j] += av[i] * bv[j];
        }
        __syncthreads();
    }
    const float4 biasA = *(const float4*)&b_in[n0 + tn4];
    const float4 biasB = *(const float4*)&b_in[n0 + tn4 + 64];
    #pragma unroll
    for (int i = 0; i < 8; ++i) {
        const int m = m0 + (i < 4 ? tm4 + i : 64 + tm4 + i - 4);
        float4 o0, o1;
        o0.x = acc[i][0] + biasA.x; o0.y = acc[i][1] + biasA.y;
        o0.z = acc[i][2] + biasA.z; o0.w = acc[i][3] + biasA.w;
        o1.x = acc[i][4] + biasB.x; o1.y = acc[i][5] + biasB.y;
        o1.z = acc[i][6] + biasB.z; o1.w = acc[i][7] + biasB.w;
        *(float4*)&v[(size_t)m * CH + n0 + tn4]      = o0;
        *(float4*)&v[(size_t)m * CH + n0 + tn4 + 64] = o1;
    }
}

// ---------------------------------------------------------------------------
// Fused depthwise 3x3 + bias + LayerNorm(C) + exact GELU -> f (NHWC)
// ---------------------------------------------------------------------------
__global__ __launch_bounds__(256)
void dw_ln_gelu_kernel(const float* __restrict__ x,
                       const float* __restrict__ dw_w,
                       const float* __restrict__ dw_b,
                       const float* __restrict__ ln_g,
                       const float* __restrict__ ln_b,
                       float* __restrict__ f)
{
    __shared__ float tile[WDIM][CH + 1];
    __shared__ float red1[WDIM][4], red2[WDIM][4];
    __shared__ float meanA[WDIM], rstdA[WDIM];

    const int h = blockIdx.x;
    const int b = blockIdx.y;
    const int t = threadIdx.x;
    const int lane = t & 63;
    const int wv   = t >> 6;

    for (int cg = 0; cg < CH / 4; ++cg) {
        const int c = cg * 4 + wv;
        const float* xp = x + ((size_t)b * CH + c) * HW;
        float rowv[3];
        #pragma unroll
        for (int r = 0; r < 3; ++r) {
            const int hh = h + r - 1;
            rowv[r] = (lane < WDIM && hh >= 0 && hh < HDIM) ? xp[hh * WDIM + lane] : 0.0f;
        }
        const float* wp = dw_w + c * 9;
        float acc = dw_b[c];
        #pragma unroll
        for (int r = 0; r < 3; ++r) {
            float L = __shfl_up(rowv[r], 1);
            float R = __shfl_down(rowv[r], 1);
            if (lane == 0) L = 0.0f;
            acc += L * wp[r * 3 + 0] + rowv[r] * wp[r * 3 + 1] + R * wp[r * 3 + 2];
        }
        if (lane < WDIM)
            tile[lane][c] = acc;
    }
    __syncthreads();

    if (t < 224) {
        const int p = t >> 2, q = t & 3;
        float s1 = 0.0f, s2 = 0.0f;
        #pragma unroll 8
        for (int i = 0; i < 64; ++i) {
            const float v = tile[p][q * 64 + i];
            s1 += v; s2 += v * v;
        }
        red1[p][q] = s1; red2[p][q] = s2;
    }
    __syncthreads();
    if (t < WDIM) {
        const float s1 = red1[t][0] + red1[t][1] + red1[t][2] + red1[t][3];
        const float s2 = red2[t][0] + red2[t][1] + red2[t][2] + red2[t][3];
        const float m = s1 * (1.0f / 256.0f);
        const float var = s2 * (1.0f / 256.0f) - m * m;
        meanA[t] = m;
        rstdA[t] = rsqrtf(var + 1e-5f);
    }
    __syncthreads();

    const float gam = ln_g[t], bet = ln_b[t];
    const size_t n0 = (size_t)(b * HDIM + h) * WDIM;
    for (int p = 0; p < WDIM; ++p) {
        const float xn = (tile[p][t] - meanA[p]) * rstdA[p] * gam + bet;
        const float g = 0.5f * xn * (1.0f + erff(xn * 0.70710678118654752f));
        f[(n0 + p) * CH + t] = g;
    }
}

// ---------------------------------------------------------------------------
// Transpose + hi/lo bf16 split of w_out: [k][n] fp32 -> wt_hi/wt_lo [n][k] bf16.
// ---------------------------------------------------------------------------
__global__ __launch_bounds__(256)
void wt_split_kernel(const float* __restrict__ w,
                     unsigned short* __restrict__ hi,
                     unsigned short* __restrict__ lo)
{
    __shared__ float lds[64][68];
    const int kt = blockIdx.x * 64, nt = blockIdx.y * 64;
    const int t = threadIdx.x;
    #pragma unroll
    for (int p = 0; p < 4; ++p) {
        const int kr = (t >> 4) + p * 16, nc = (t & 15) * 4;
        *(float4*)&lds[kr][nc] = *(const float4*)(w + (size_t)(kt + kr) * CH + nt + nc);
    }
    __syncthreads();
    const int nl = t >> 2, kc = (t & 3) * 16;
    #pragma unroll
    for (int j = 0; j < 16; j += 2) {
        const float f0 = lds[kc + j][nl], f1 = lds[kc + j + 1][nl];
        unsigned int hp, lp;
        split2(f0, f1, hp, lp);
        *(unsigned int*)&hi[(size_t)(nt + nl) * CH + kt + kc + j] = hp;
        *(unsigned int*)&lo[(size_t)(nt + nl) * CH + kt + kc + j] = lp;
    }
}

// ---------------------------------------------------------------------------
// Transpose + split of [w_off | w_mask] -> wt2_hi/lo [256 n_pad][256 k] bf16.
// Lane = n (coalesced reads over source rows); rows n>=216 zeroed.
// Block b handles k in [b*16, b*16+16).
// ---------------------------------------------------------------------------
__global__ __launch_bounds__(256)
void wt2_split_kernel(const float* __restrict__ w_off,   // [256][144]
                      const float* __restrict__ w_mask,  // [256][72]
                      unsigned short* __restrict__ hi,
                      unsigned short* __restrict__ lo)
{
    const int n = threadIdx.x;
    const int k0 = blockIdx.x * 16;
    #pragma unroll
    for (int j = 0; j < 16; j += 2) {
        const int k = k0 + j;
        float f0 = 0.0f, f1 = 0.0f;
        if (n < NOFF) {
            f0 = w_off[(size_t)k * NOFF + n];
            f1 = w_off[(size_t)(k + 1) * NOFF + n];
        } else if (n < NTOT) {
            f0 = w_mask[(size_t)k * NMSK + (n - NOFF)];
            f1 = w_mask[(size_t)(k + 1) * NMSK + (n - NOFF)];
        }
        unsigned int hp, lp;
        split2(f0, f1, hp, lp);
        *(unsigned int*)&hi[(size_t)n * CH + k] = hp;
        *(unsigned int*)&lo[(size_t)n * CH + k] = lp;
    }
}

// ---------------------------------------------------------------------------
// Fused offset+mask GEMM via bf16 MFMA (split hi/lo, 3 products).
// Same validated structure as gemm_out_mfma: barrier-free, no LDS; weights
// (A-operand) from wt2_[hi|lo][n][k]; f rows (B-operand) split in-register.
// Block 256 thr = 4 waves, tile 256m x 64n; grid (MTOT/256, 4) covers n<256,
// stores skipped for n >= 216.
// ---------------------------------------------------------------------------
__global__ __launch_bounds__(256)
void gemm_offmask_mfma(const float* __restrict__ A,            // f [MTOT,256]
                       const unsigned short* __restrict__ whi, // [256][256] bf16
                       const unsigned short* __restrict__ wlo,
                       const float* __restrict__ b_off,
                       const float* __restrict__ b_mask,
                       float* __restrict__ offb,               // [MTOT,144]
                       float* __restrict__ mskb)               // [MTOT,72]
{
    const int m0 = blockIdx.x * 256;
    const int n0 = blockIdx.y * 64;
    const int t = threadIdx.x;
    const int lane = t & 63, wv = t >> 6;
    const int mblk = m0 + wv * 64;
    const int fm = lane & 15;
    const int q  = lane >> 4;

    f32x4 acc[4][4];              // [nt][mt]
    const f32x4 zero = {0.0f, 0.0f, 0.0f, 0.0f};
    #pragma unroll
    for (int i = 0; i < 4; ++i)
        #pragma unroll
        for (int j = 0; j < 4; ++j) acc[i][j] = zero;

    const float* arow[4];
    const unsigned short* wrh[4];
    const unsigned short* wrl[4];
    #pragma unroll
    for (int mt = 0; mt < 4; ++mt)
        arow[mt] = A + (size_t)(mblk + mt*16 + fm) * CH + q * 8;
    #pragma unroll
    for (int nt = 0; nt < 4; ++nt) {
        wrh[nt] = whi + (size_t)(n0 + nt*16 + fm) * CH + q * 8;
        wrl[nt] = wlo + (size_t)(n0 + nt*16 + fm) * CH + q * 8;
    }

    for (int k0 = 0; k0 < CH; k0 += 32) {
        s16x8 wh[4], wl[4], sh[4], sl[4];
        #pragma unroll
        for (int nt = 0; nt < 4; ++nt) {
            wh[nt] = *(const s16x8*)(wrh[nt] + k0);
            wl[nt] = *(const s16x8*)(wrl[nt] + k0);
        }
        #pragma unroll
        for (int mt = 0; mt < 4; ++mt) {
            const f32x4 r0 = *(const f32x4*)(arow[mt] + k0);
            const f32x4 r1 = *(const f32x4*)(arow[mt] + k0 + 4);
            union { s16x8 v; unsigned int u[4]; } ph, pl;
            split2(r0[0], r0[1], ph.u[0], pl.u[0]);
            split2(r0[2], r0[3], ph.u[1], pl.u[1]);
            split2(r1[0], r1[1], ph.u[2], pl.u[2]);
            split2(r1[2], r1[3], ph.u[3], pl.u[3]);
            sh[mt] = ph.v; sl[mt] = pl.v;
        }
        #pragma unroll
        for (int nt = 0; nt < 4; ++nt)
            #pragma unroll
            for (int mt = 0; mt < 4; ++mt) {
                acc[nt][mt] = __builtin_amdgcn_mfma_f32_16x16x32_bf16(wh[nt], sh[mt], acc[nt][mt], 0, 0, 0);
                acc[nt][mt] = __builtin_amdgcn_mfma_f32_16x16x32_bf16(wh[nt], sl[mt], acc[nt][mt], 0, 0, 0);
                acc[nt][mt] = __builtin_amdgcn_mfma_f32_16x16x32_bf16(wl[nt], sh[mt], acc[nt][mt], 0, 0, 0);
            }
    }

    // epilogue: lane holds D[n = q*4+r][m = fm] per (nt, mt)
    #pragma unroll
    for (int nt = 0; nt < 4; ++nt) {
        #pragma unroll
        for (int r = 0; r < 4; ++r) {
            const int n = n0 + nt*16 + q*4 + r;
            if (n >= NTOT) continue;
            const float bs = (n < NOFF) ? b_off[n] : b_mask[n - NOFF];
            #pragma unroll
            for (int mt = 0; mt < 4; ++mt) {
                const int m = mblk + mt*16 + fm;
                const float val = acc[nt][mt][r] + bs;
                if (n < NOFF) offb[(size_t)m * NOFF + n] = val;
                else          mskb[(size_t)m * NMSK + (n - NOFF)] = val;
            }
        }
    }
}

// ---------------------------------------------------------------------------
// Deformable sampling (unchanged).
// ---------------------------------------------------------------------------
__global__ __launch_bounds__(256)
void sample_kernel(const float* __restrict__ v,
                   const float* __restrict__ offb,
                   const float* __restrict__ mskb,
                   float* __restrict__ s)
{
    __shared__ alignas(16) float loff[POSB][NOFF];
    __shared__ alignas(16) float lmsk[POSB][NMSK];
    __shared__ alignas(16) float wtab[POSB][GRP*NP][4];
    __shared__ alignas(16) int   itab[POSB][GRP*NP][4];

    const int n0 = blockIdx.x * POSB;
    const int t = threadIdx.x;

    if (t < POSB * (NOFF/4)) {
        const int q = t / (NOFF/4), r = t % (NOFF/4);
        *(float4*)&loff[q][r*4] = *(const float4*)&offb[(size_t)(n0+q)*NOFF + r*4];
    } else if (t < POSB * (NOFF/4) + POSB * (NMSK/4)) {
        const int u = t - POSB * (NOFF/4);
        const int q = u / (NMSK/4), r = u % (NMSK/4);
        *(float4*)&lmsk[q][r*4] = *(const float4*)&mskb[(size_t)(n0+q)*NMSK + r*4];
    }
    __syncthreads();

    if (t < POSB * GRP) {
        const int q = t >> 3, g = t & 7;
        float* mm = &lmsk[q][g * NP];
        float mx = -1e30f;
        #pragma unroll
        for (int p = 0; p < NP; ++p) mx = fmaxf(mx, mm[p]);
        float sum = 0.0f;
        #pragma unroll
        for (int p = 0; p < NP; ++p) { const float e = __expf(mm[p] - mx); mm[p] = e; sum += e; }
        const float inv = 1.0f / sum;
        #pragma unroll
        for (int p = 0; p < NP; ++p) mm[p] *= inv;
    }
    __syncthreads();

    for (int u = t; u < POSB * GRP * NP; u += 256) {
        const int q = u / (GRP*NP), j = u % (GRP*NP);
        const int g = j / NP, p = j % NP;
        const int n = n0 + q;
        const int hw = n % HW;
        const int h = hw / WDIM, w = hw % WDIM;
        const float ox = loff[q][g*18 + p*2 + 0];
        const float oy = loff[q][g*18 + p*2 + 1];
        const float m  = lmsk[q][g*NP + p];
        const float px = (float)(w + p/3) + ox;
        const float py = (float)(h + p%3) + oy;
        const float fx = floorf(px), fy = floorf(py);
        const float wx = px - fx, wy = py - fy;
        const int x0 = (int)fx, y0 = (int)fy;
        const int x1 = x0 + 1, y1 = y0 + 1;
        const float vx0 = (x0 >= 1 && x0 < 57) ? 1.0f : 0.0f;
        const float vx1 = (x1 >= 1 && x1 < 57) ? 1.0f : 0.0f;
        const float vy0 = (y0 >= 1 && y0 < 57) ? 1.0f : 0.0f;
        const float vy1 = (y1 >= 1 && y1 < 57) ? 1.0f : 0.0f;
        const int x0c = min(max(x0, 1), 56), x1c = min(max(x1, 1), 56);
        const int y0c = min(max(y0, 1), 56), y1c = min(max(y1, 1), 56);
        wtab[q][j][0] = m * (1.0f-wx) * (1.0f-wy) * vx0 * vy0;
        wtab[q][j][1] = m * wx        * (1.0f-wy) * vx1 * vy0;
        wtab[q][j][2] = m * (1.0f-wx) * wy        * vx0 * vy1;
        wtab[q][j][3] = m * wx        * wy        * vx1 * vy1;
        itab[q][j][0] = ((y0c-1)*WDIM + (x0c-1)) * CH;
        itab[q][j][1] = ((y0c-1)*WDIM + (x1c-1)) * CH;
        itab[q][j][2] = ((y1c-1)*WDIM + (x0c-1)) * CH;
        itab[q][j][3] = ((y1c-1)*WDIM + (x1c-1)) * CH;
    }
    __syncthreads();

    const int q = t >> 6, lane = t & 63;
    const int n = n0 + q;
    const int b = n / HW;
    const int g = lane >> 3;
    const float* vb = v + (size_t)b*HW*CH + lane*4;
    float4 acc = {0.0f, 0.0f, 0.0f, 0.0f};
    #pragma unroll
    for (int p = 0; p < NP; ++p) {
        const int j = g*NP + p;
        const float4 wv = *(const float4*)&wtab[q][j][0];
        const int4  iv = *(const int4*)&itab[q][j][0];
        const float4 c0 = *(const float4*)(vb + iv.x);
        const float4 c1 = *(const float4*)(vb + iv.y);
        const float4 c2 = *(const float4*)(vb + iv.z);
        const float4 c3 = *(const float4*)(vb + iv.w);
        acc.x += wv.x*c0.x + wv.y*c1.x + wv.z*c2.x + wv.w*c3.x;
        acc.y += wv.x*c0.y + wv.y*c1.y + wv.z*c2.y + wv.w*c3.y;
        acc.z += wv.x*c0.z + wv.y*c1.z + wv.z*c2.z + wv.w*c3.z;
        acc.w += wv.x*c0.w + wv.y*c1.w + wv.z*c2.w + wv.w*c3.w;
    }
    *(float4*)&s[(size_t)n*CH + lane*4] = acc;
}

// ---------------------------------------------------------------------------
// GEMM out via bf16 MFMA (split hi/lo, 3 products): y = SiLU(BN(s@w_out+b)).
// ---------------------------------------------------------------------------
__global__ __launch_bounds__(256)
void gemm_out_mfma(const float* __restrict__ A,            // s [MTOT,256]
                   const unsigned short* __restrict__ whi, // [256 n][256 k] bf16
                   const unsigned short* __restrict__ wlo,
                   const float* __restrict__ bias,
                   const float* __restrict__ bn_g,
                   const float* __restrict__ bn_b,
                   const float* __restrict__ bn_mean,
                   const float* __restrict__ bn_var,
                   float* __restrict__ y)                  // [B,256,3136]
{
    const int m0 = blockIdx.x * 256;
    const int n0 = blockIdx.y * 64;
    const int t = threadIdx.x;
    const int lane = t & 63, wv = t >> 6;
    const int mblk = m0 + wv * 64;
    const int fm = lane & 15;
    const int q  = lane >> 4;

    f32x4 acc[4][4];              // [nt][mt]
    const f32x4 zero = {0.0f, 0.0f, 0.0f, 0.0f};
    #pragma unroll
    for (int i = 0; i < 4; ++i)
        #pragma unroll
        for (int j = 0; j < 4; ++j) acc[i][j] = zero;

    const float* arow[4];
    const unsigned short* wrh[4];
    const unsigned short* wrl[4];
    #pragma unroll
    for (int mt = 0; mt < 4; ++mt)
        arow[mt] = A + (size_t)(mblk + mt*16 + fm) * CH + q * 8;
    #pragma unroll
    for (int nt = 0; nt < 4; ++nt) {
        wrh[nt] = whi + (size_t)(n0 + nt*16 + fm) * CH + q * 8;
        wrl[nt] = wlo + (size_t)(n0 + nt*16 + fm) * CH + q * 8;
    }

    for (int k0 = 0; k0 < CH; k0 += 32) {
        s16x8 wh[4], wl[4], sh[4], sl[4];
        #pragma unroll
        for (int nt = 0; nt < 4; ++nt) {
            wh[nt] = *(const s16x8*)(wrh[nt] + k0);
            wl[nt] = *(const s16x8*)(wrl[nt] + k0);
        }
        #pragma unroll
        for (int mt = 0; mt < 4; ++mt) {
            const f32x4 r0 = *(const f32x4*)(arow[mt] + k0);
            const f32x4 r1 = *(const f32x4*)(arow[mt] + k0 + 4);
            union { s16x8 v; unsigned int u[4]; } ph, pl;
            split2(r0[0], r0[1], ph.u[0], pl.u[0]);
            split2(r0[2], r0[3], ph.u[1], pl.u[1]);
            split2(r1[0], r1[1], ph.u[2], pl.u[2]);
            split2(r1[2], r1[3], ph.u[3], pl.u[3]);
            sh[mt] = ph.v; sl[mt] = pl.v;
        }
        #pragma unroll
        for (int nt = 0; nt < 4; ++nt)
            #pragma unroll
            for (int mt = 0; mt < 4; ++mt) {
                acc[nt][mt] = __builtin_amdgcn_mfma_f32_16x16x32_bf16(wh[nt], sh[mt], acc[nt][mt], 0, 0, 0);
                acc[nt][mt] = __builtin_amdgcn_mfma_f32_16x16x32_bf16(wh[nt], sl[mt], acc[nt][mt], 0, 0, 0);
                acc[nt][mt] = __builtin_amdgcn_mfma_f32_16x16x32_bf16(wl[nt], sh[mt], acc[nt][mt], 0, 0, 0);
            }
    }

    #pragma unroll
    for (int nt = 0; nt < 4; ++nt) {
        #pragma unroll
        for (int r = 0; r < 4; ++r) {
            const int n = n0 + nt*16 + q*4 + r;
            const float sc = bn_g[n] * rsqrtf(bn_var[n] + 1e-5f);
            const float sb = bn_b[n] - bn_mean[n] * sc;
            const float bs = bias[n];
            #pragma unroll
            for (int mt = 0; mt < 4; ++mt) {
                const int mm = mblk + mt*16;
                const size_t base = (size_t)(mm / HW) * CH * HW + (mm % HW);
                float val = (acc[nt][mt][r] + bs) * sc + sb;
                y[base + (size_t)n * HW + fm] = val / (1.0f + expf(-val));
            }
        }
    }
}

extern "C" void kernel_launch(void* const* d_in, const int* in_sizes, int n_in,
                              void* d_out, int out_size, void* d_ws, size_t ws_size,
                              hipStream_t stream) {
    const float* x      = (const float*)d_in[0];
    const float* w_in   = (const float*)d_in[1];
    const float* b_in   = (const float*)d_in[2];
    const float* dw_w   = (const float*)d_in[3];
    const float* dw_b   = (const float*)d_in[4];
    const float* ln_g   = (const float*)d_in[5];
    const float* ln_b   = (const float*)d_in[6];
    const float* w_off  = (const float*)d_in[7];
    const float* b_off  = (const float*)d_in[8];
    const float* w_mask = (const float*)d_in[9];
    const float* b_mask = (const float*)d_in[10];
    const float* w_out  = (const float*)d_in[11];
    const float* b_out  = (const float*)d_in[12];
    const float* bn_g   = (const float*)d_in[13];
    const float* bn_b   = (const float*)d_in[14];
    const float* bn_mean= (const float*)d_in[15];
    const float* bn_var = (const float*)d_in[16];
    float* out = (float*)d_out;

    float* ws   = (float*)d_ws;
    float* v    = ws;                                   // MTOT*CH
    float* f    = v + (size_t)MTOT*CH;                  // MTOT*CH
    float* offb = f + (size_t)MTOT*CH;                  // MTOT*NOFF
    float* mskb = offb + (size_t)MTOT*NOFF;             // MTOT*NMSK
    float* s    = f;                                    // reuse f buffer
    unsigned short* wt_hi  = (unsigned short*)(mskb + (size_t)MTOT*NMSK);  // 256*256 bf16
    unsigned short* wt_lo  = wt_hi + CH*CH;
    unsigned short* wt2_hi = wt_lo + CH*CH;                                // 256*256 bf16
    unsigned short* wt2_lo = wt2_hi + CH*CH;

    wt_split_kernel<<<dim3(4, 4), dim3(256), 0, stream>>>(w_out, wt_hi, wt_lo);
    wt2_split_kernel<<<dim3(16), dim3(256), 0, stream>>>(w_off, w_mask, wt2_hi, wt2_lo);
    gemm_in_kernel<<<dim3(MTOT/128, CH/128), dim3(256), 0, stream>>>(x, w_in, b_in, v);
    dw_ln_gelu_kernel<<<dim3(HDIM, BATCH), dim3(256), 0, stream>>>(x, dw_w, dw_b, ln_g, ln_b, f);
    gemm_offmask_mfma<<<dim3(MTOT/256, 4), dim3(256), 0, stream>>>(
        f, wt2_hi, wt2_lo, b_off, b_mask, offb, mskb);
    sample_kernel<<<dim3(MTOT/POSB), dim3(256), 0, stream>>>(v, offb, mskb, s);
    gemm_out_mfma<<<dim3(MTOT/256, CH/64), dim3(256), 0, stream>>>(
        s, wt_hi, wt_lo, b_out, bn_g, bn_b, bn_mean, bn_var, out);
}